// Round 11
// baseline (51.156 us; speedup 1.0000x reference)
//
#include <hip/hip_runtime.h>

#define S_LEN 1024
#define D_TOT 512
#define D_E   448

typedef short bf16x8 __attribute__((ext_vector_type(8)));
typedef float f32x4  __attribute__((ext_vector_type(4)));
typedef unsigned short u16;

__device__ __forceinline__ float frcp(float x) {
  float r; asm("v_rcp_f32 %0, %1" : "=v"(r) : "v"(x)); return r;
}

__device__ __forceinline__ float wave_sum64(float v) {
#pragma unroll
  for (int o = 32; o > 0; o >>= 1) v += __shfl_xor(v, o);
  return v;
}

__device__ __forceinline__ u16 bf16rne(float f) {
  unsigned u = __builtin_bit_cast(unsigned, f);
  return (u16)((u + 0x7fffu + ((u >> 16) & 1u)) >> 16);
}

__device__ __forceinline__ void bsplit(float f, u16 &h, u16 &l) {
  unsigned u  = __builtin_bit_cast(unsigned, f);
  unsigned ur = u + 0x7fffu + ((u >> 16) & 1u);
  h = (u16)(ur >> 16);
  float fh = __builtin_bit_cast(float, ur & 0xffff0000u);
  float r  = f - fh;
  l = bf16rne(r);
}

__device__ __forceinline__ void bsplit8(float4 a, float4 b, uint4 &h, uint4 &l) {
  u16 h0,h1,h2,h3,h4,h5,h6,h7, l0,l1,l2,l3,l4,l5,l6,l7;
  bsplit(a.x,h0,l0); bsplit(a.y,h1,l1); bsplit(a.z,h2,l2); bsplit(a.w,h3,l3);
  bsplit(b.x,h4,l4); bsplit(b.y,h5,l5); bsplit(b.z,h6,l6); bsplit(b.w,h7,l7);
  h.x = (unsigned)h0 | ((unsigned)h1<<16); h.y = (unsigned)h2 | ((unsigned)h3<<16);
  h.z = (unsigned)h4 | ((unsigned)h5<<16); h.w = (unsigned)h6 | ((unsigned)h7<<16);
  l.x = (unsigned)l0 | ((unsigned)l1<<16); l.y = (unsigned)l2 | ((unsigned)l3<<16);
  l.z = (unsigned)l4 | ((unsigned)l5<<16); l.w = (unsigned)l6 | ((unsigned)l7<<16);
}

__device__ __forceinline__ uint4 rne8(float4 a, float4 b) {
  uint4 h;
  h.x = (unsigned)bf16rne(a.x) | ((unsigned)bf16rne(a.y)<<16);
  h.y = (unsigned)bf16rne(a.z) | ((unsigned)bf16rne(a.w)<<16);
  h.z = (unsigned)bf16rne(b.x) | ((unsigned)bf16rne(b.y)<<16);
  h.w = (unsigned)bf16rne(b.z) | ((unsigned)bf16rne(b.w)<<16);
  return h;
}

#define MFMA2(ACC)                                                                              \
  _Pragma("unroll") for (int i_ = 0; i_ < 2; ++i_)                                              \
  _Pragma("unroll") for (int j_ = 0; j_ < 2; ++j_) {                                            \
    ACC[i_][j_] = __builtin_amdgcn_mfma_f32_16x16x32_bf16(fAh[i_], fBh[j_], ACC[i_][j_],0,0,0); \
    ACC[i_][j_] = __builtin_amdgcn_mfma_f32_16x16x32_bf16(fAh[i_], fBl[j_], ACC[i_][j_],0,0,0); \
  }

#define MFMA1(ACC)                                                                              \
  _Pragma("unroll") for (int i_ = 0; i_ < 2; ++i_)                                              \
  _Pragma("unroll") for (int j_ = 0; j_ < 2; ++j_)                                              \
    ACC[i_][j_] = __builtin_amdgcn_mfma_f32_16x16x32_bf16(fAh[i_], fBh[j_], ACC[i_][j_],0,0,0);

// ================= wprod: W2 = Wo @ Wv (NN), bvo = Wo @ bv =================
__global__ __launch_bounds__(512,4) void wprod_mfma(
    const float* __restrict__ wo, const float* __restrict__ wv,
    const float* __restrict__ bv,
    float* __restrict__ W2, float* __restrict__ bvo)
{
  __shared__ __align__(16) char shm_[34816];
  u16* stg = (u16*)shm_;
  float* fbuf = (float*)shm_;
  const int t = threadIdx.x, lane = t & 63, wave = t >> 6;
  const int mBase = blockIdx.y << 6, nBase = blockIdx.x << 6;
  const int kg = t >> 8, sub = t & 255;
  const int kgw = wave >> 2, wr = (wave >> 1) & 1, wc = wave & 1;

  const int srow = sub >> 2, scol = (sub & 3) << 3;
  const float* Ag = wo + (size_t)(mBase + srow) * D_TOT + kg * 256 + scol;
  const int bk = sub & 31, bng = sub >> 5;
  const float* Bg = wv + (size_t)(kg * 256 + bk) * D_TOT + nBase + bng * 8;

  const int sA  = kg * 7680 + srow * 40 + scol;
  const int sBh = kg * 7680 + 2560;
  const int sBl = kg * 7680 + 5120;
  const int fa  = kgw * 7680 + (wr * 32 + (lane & 15)) * 40 + ((lane >> 4) << 3);
  const int fbh = kgw * 7680 + 2560 + (wc * 32 + (lane & 15)) * 40 + ((lane >> 4) << 3);

  f32x4 zero = {0.f,0.f,0.f,0.f};
  f32x4 acc[2][2] = {{zero,zero},{zero,zero}};
#pragma unroll
  for (int r = 0; r < 8; ++r) {
    float4 a0 = *(const float4*)(Ag + r*32);
    float4 a1 = *(const float4*)(Ag + r*32 + 4);
    float4 w0 = *(const float4*)(Bg + (size_t)r*32*D_TOT);
    float4 w1 = *(const float4*)(Bg + (size_t)r*32*D_TOT + 4);
    __syncthreads();
    *(uint4*)&stg[sA] = rne8(a0, a1);
    float bb[8] = {w0.x,w0.y,w0.z,w0.w,w1.x,w1.y,w1.z,w1.w};
#pragma unroll
    for (int j = 0; j < 8; ++j) {
      u16 h,l; bsplit(bb[j], h, l);
      stg[sBh + (bng*8 + j)*40 + bk] = h;
      stg[sBl + (bng*8 + j)*40 + bk] = l;
    }
    __syncthreads();
    bf16x8 fAh[2], fBh[2], fBl[2];
#pragma unroll
    for (int i = 0; i < 2; ++i) {
      fAh[i] = *(const bf16x8*)&stg[fa         + i*640];
      fBh[i] = *(const bf16x8*)&stg[fbh        + i*640];
      fBl[i] = *(const bf16x8*)&stg[fbh + 2560 + i*640];
    }
    MFMA2(acc);
  }

  __syncthreads();
  {
    const int r0 = wr*32 + ((lane>>4)<<2);
    const int c0 = wc*32 + (lane&15);
#pragma unroll
    for (int i = 0; i < 2; ++i)
#pragma unroll
      for (int j = 0; j < 2; ++j)
#pragma unroll
        for (int g = 0; g < 4; ++g)
          fbuf[kgw*4352 + (r0 + i*16 + g)*68 + c0 + j*16] = acc[i][j][g];
  }
  __syncthreads();
  const int erow = wave << 3;
#pragma unroll
  for (int r = 0; r < 8; ++r) {
    float v = fbuf[(erow+r)*68 + lane] + fbuf[4352 + (erow+r)*68 + lane];
    W2[(size_t)(mBase + erow + r)*D_TOT + nBase + lane] = v;
  }

  if (blockIdx.x == 0) {
    __syncthreads();
    const int m = t >> 3, sl = t & 7;
    const float* wrow = wo + (size_t)(mBase + m)*D_TOT + sl*64;
    float s_ = 0.f;
#pragma unroll
    for (int k = 0; k < 64; ++k) s_ += wrow[k] * bv[sl*64 + k];
    fbuf[m*8 + sl] = s_;
    __syncthreads();
    if (t < 64) {
      float s2 = 0.f;
#pragma unroll
      for (int c = 0; c < 8; ++c) s2 += fbuf[t*8 + c];
      bvo[mBase + t] = s2;
    }
  }
}

// ================= QKV: z=0/1 -> q/k stats; z=2 -> voT (hi-only, transposed) =================
__global__ __launch_bounds__(512,4) void qkv_mfma(
    const float* __restrict__ x,
    const float* __restrict__ wq, const float* __restrict__ bq,
    const float* __restrict__ wk, const float* __restrict__ bk,
    const float* __restrict__ w2, const float* __restrict__ bvo,
    u16* __restrict__ Qch,
    u16* __restrict__ Kch, u16* __restrict__ Kcl,
    u16* __restrict__ voTh,
    float* __restrict__ qnpart, float* __restrict__ knpart,
    float* __restrict__ uh2a, float* __restrict__ vh2a)
{
  __shared__ __align__(16) u16 stage[2][15360];
  float* fbuf = (float*)stage;
  const int z = blockIdx.z;
  const float* W; const float* bias;
  if (z == 0)      { W = wq; bias = bq; }
  else if (z == 1) { W = wk; bias = bk; }
  else             { W = w2; bias = bvo; }
  const int mBase = blockIdx.y << 6, nBase = blockIdx.x << 6;
  const int t = threadIdx.x, lane = t & 63, wave = t >> 6;
  const int kg = t >> 8, sub = t & 255;
  const int srow = sub >> 2, scol = (sub & 3) << 3;
  const int kgw = wave >> 2, wr = (wave >> 1) & 1, wc = wave & 1;

  const float* Ag = x + (size_t)(mBase + srow) * D_TOT + scol + kg * 256;
  const float* Bg = W + (size_t)(nBase + srow) * D_TOT + scol + kg * 256;

  const int sb = kg * 7680 + srow * 40 + scol;
  const int fa = kgw * 7680 + (wr * 32 + (lane & 15)) * 40 + ((lane >> 4) << 3);
  const int fb = kgw * 7680 + 2560 + (wc * 32 + (lane & 15)) * 40 + ((lane >> 4) << 3);

  float4 a0 = *(const float4*)Ag, a1 = *(const float4*)(Ag + 4);
  float4 b0 = *(const float4*)Bg, b1 = *(const float4*)(Bg + 4);
  {
    uint4 hB,lB; bsplit8(b0,b1,hB,lB);
    *(uint4*)&stage[0][sb       ] = rne8(a0,a1);
    *(uint4*)&stage[0][sb + 2560] = hB;
    *(uint4*)&stage[0][sb + 5120] = lB;
  }
  a0 = *(const float4*)(Ag + 32); a1 = *(const float4*)(Ag + 36);
  b0 = *(const float4*)(Bg + 32); b1 = *(const float4*)(Bg + 36);

  f32x4 zero = {0.f,0.f,0.f,0.f};
  f32x4 acc[2][2] = {{zero,zero},{zero,zero}};
#pragma unroll
  for (int r = 0; r < 8; ++r) {
    __syncthreads();
    const u16* bufr = stage[r & 1];
    bf16x8 fAh[2], fBh[2], fBl[2];
#pragma unroll
    for (int i = 0; i < 2; ++i) {
      fAh[i] = *(const bf16x8*)&bufr[fa        + i*640];
      fBh[i] = *(const bf16x8*)&bufr[fb        + i*640];
      fBl[i] = *(const bf16x8*)&bufr[fb + 2560 + i*640];
    }
    if (r + 1 < 8) {
      u16* bufw = stage[(r + 1) & 1];
      uint4 hB,lB; bsplit8(b0,b1,hB,lB);
      *(uint4*)&bufw[sb       ] = rne8(a0,a1);
      *(uint4*)&bufw[sb + 2560] = hB;
      *(uint4*)&bufw[sb + 5120] = lB;
      if (r + 2 < 8) {
        const int o = (r + 2) * 32;
        a0 = *(const float4*)(Ag + o); a1 = *(const float4*)(Ag + o + 4);
        b0 = *(const float4*)(Bg + o); b1 = *(const float4*)(Bg + o + 4);
      }
    }
    MFMA2(acc);
  }

  __syncthreads();
  {
    const int r0 = wr*32 + ((lane>>4)<<2);
    const int c0 = wc*32 + (lane&15);
#pragma unroll
    for (int i = 0; i < 2; ++i)
#pragma unroll
      for (int j = 0; j < 2; ++j)
#pragma unroll
        for (int g = 0; g < 4; ++g)
          fbuf[kgw*4352 + (r0 + i*16 + g)*68 + c0 + j*16] = acc[i][j][g];
  }
  __syncthreads();
  const int erow = wave << 3;
  float val[8];
  {
    const float b = bias[nBase + lane];
#pragma unroll
    for (int r = 0; r < 8; ++r)
      val[r] = fbuf[(erow+r)*68 + lane] + fbuf[4352 + (erow+r)*68 + lane] + b;
  }

  if (z == 2) {
    u16 hh[8];
#pragma unroll
    for (int r = 0; r < 8; ++r) hh[r] = bf16rne(val[r]);
    const size_t off = (size_t)(nBase + lane) * S_LEN + mBase + erow;
    ushort4 p0{hh[0],hh[1],hh[2],hh[3]}, p1{hh[4],hh[5],hh[6],hh[7]};
    *(ushort4*)(voTh + off) = p0; *(ushort4*)(voTh + off + 4) = p1;
  } else if (z == 1) {
    if (blockIdx.x < 7) {
#pragma unroll
      for (int r = 0; r < 8; ++r) {
        const int s = mBase + erow + r;
        u16 h,l; bsplit(val[r],h,l);
        Kch[(size_t)s*D_TOT + nBase + lane] = h;
        Kcl[(size_t)s*D_TOT + nBase + lane] = l;
        float p = wave_sum64(val[r]*val[r]);
        if (lane == 0) knpart[s*8 + blockIdx.x] = p;
      }
    } else {
#pragma unroll
      for (int r = 0; r < 8; ++r) {
        const int s = mBase + erow + r;
        float n2 = wave_sum64(val[r]*val[r]);
        float nn = sqrtf(n2);
        float n  = fmaxf(nn, 1e-5f);
        float e2n = __expf(2.f*n);
        float th  = 1.f - 2.f*frcp(e2n + 1.f);
        float rn  = frcp(n);
        float pn  = th * nn * rn;
        float scale = fminf(0.999f * frcp(fmaxf(pn, 1e-5f)), 1.f);
        float u = th * rn * scale * val[r];
        float un = pn * scale;
        u16 h,l; bsplit(u,h,l);
        Kch[(size_t)s*D_TOT + nBase + lane] = h;
        Kcl[(size_t)s*D_TOT + nBase + lane] = l;
        if (lane == 0) vh2a[s] = un*un;
      }
    }
  } else {
    if (blockIdx.x < 7) {
#pragma unroll
      for (int r = 0; r < 8; ++r) {
        const int s = mBase + erow + r;
        Qch[(size_t)s*D_TOT + nBase + lane] = bf16rne(val[r]);
        float p = wave_sum64(val[r]*val[r]);
        if (lane == 0) qnpart[s*8 + blockIdx.x] = p;
      }
    } else {
#pragma unroll
      for (int r = 0; r < 8; ++r) {
        const int s = mBase + erow + r;
        float n2 = wave_sum64(val[r]*val[r]);
        float nn = sqrtf(n2);
        float n  = fmaxf(nn, 1e-5f);
        float e2n = __expf(2.f*n);
        float th  = 1.f - 2.f*frcp(e2n + 1.f);
        float rn  = frcp(n);
        float pn  = th * nn * rn;
        float scale = fminf(0.999f * frcp(fmaxf(pn, 1e-5f)), 1.f);
        float u = th * rn * scale * val[r];
        float un = pn * scale;
        Qch[(size_t)s*D_TOT + nBase + lane] = bf16rne(u);
        if (lane == 0) uh2a[s] = un*un;
      }
    }
  }
}

// ================= scores + exp + partial rowsums =================
__global__ __launch_bounds__(512,4) void score_mfma(
    const u16* __restrict__ Qch,
    const u16* __restrict__ Kch, const u16* __restrict__ Kcl,
    const float* __restrict__ qnpart, const float* __restrict__ knpart,
    const float* __restrict__ uh2a, const float* __restrict__ vh2a,
    const float* __restrict__ alpha_u,
    u16* __restrict__ Eh, float* __restrict__ rowpart)
{
  __shared__ __align__(16) char shm_[69632];
  __shared__ float rowscal[256];
  u16* stg = (u16*)shm_;
  float* fbuf = (float*)shm_;
  const int t = threadIdx.x, lane = t & 63, wave = t >> 6;
  const int mBase = blockIdx.y << 6, nBase = blockIdx.x << 6;
  if (t < 64) {
    float s_ = 0.f;
#pragma unroll
    for (int c = 0; c < 7; ++c) s_ += qnpart[(mBase+t)*8 + c];
    rowscal[t] = s_;
  } else if (t < 128) {
    float s_ = 0.f;
#pragma unroll
    for (int c = 0; c < 7; ++c) s_ += knpart[(nBase+t-64)*8 + c];
    rowscal[t] = s_;
  } else if (t < 192) rowscal[t] = uh2a[mBase + t - 128];
  else if (t < 256)   rowscal[t] = vh2a[nBase + t - 192];

  const int kg = t >> 8, sub = t & 255;
  const int srow = sub >> 2, scol = (sub & 3) << 3;
  const int kgw = wave >> 2, wr = (wave >> 1) & 1, wc = wave & 1;
  const u16* Agh = Qch + (size_t)(mBase+srow)*D_TOT + scol;
  const u16* Bgh = Kch + (size_t)(nBase+srow)*D_TOT + scol;
  const u16* Bgl = Kcl + (size_t)(nBase+srow)*D_TOT + scol;

  const int sb  = kg * 7680 + srow * 40 + scol;
  const int fa  = kgw * 7680 + (wr * 32 + (lane & 15)) * 40 + ((lane >> 4) << 3);
  const int fbh = kgw * 7680 + 2560 + (wc * 32 + (lane & 15)) * 40 + ((lane >> 4) << 3);

  int kb = kg * 224;
  uint4 rAh = *(const uint4*)(Agh + kb);
  uint4 rBh = *(const uint4*)(Bgh + kb), rBl = *(const uint4*)(Bgl + kb);
  *(uint4*)&stg[sb       ] = rAh;
  *(uint4*)&stg[sb + 2560] = rBh;
  *(uint4*)&stg[sb + 5120] = rBl;
  kb = kg * 224 + 32;
  rAh = *(const uint4*)(Agh + kb);
  rBh = *(const uint4*)(Bgh + kb); rBl = *(const uint4*)(Bgl + kb);

  f32x4 zero = {0.f,0.f,0.f,0.f};
  f32x4 accE[2][2] = {{zero,zero},{zero,zero}};
  f32x4 accH[2][2] = {{zero,zero},{zero,zero}};
#pragma unroll
  for (int r = 0; r < 8; ++r) {
    __syncthreads();
    const u16* bufr = stg + (r & 1) * 15360;
    bf16x8 fAh[2], fBh[2], fBl[2];
#pragma unroll
    for (int i = 0; i < 2; ++i) {
      fAh[i] = *(const bf16x8*)&bufr[fa         + i*640];
      fBh[i] = *(const bf16x8*)&bufr[fbh        + i*640];
      fBl[i] = *(const bf16x8*)&bufr[fbh + 2560 + i*640];
    }
    if (r + 1 < 8) {
      u16* bufw = stg + ((r + 1) & 1) * 15360;
      *(uint4*)&bufw[sb       ] = rAh;
      *(uint4*)&bufw[sb + 2560] = rBh;
      *(uint4*)&bufw[sb + 5120] = rBl;
      if (r + 2 < 8) {
        const int o = (r + 2 < 7) ? (kg*224 + (r+2)*32) : (448 + kg*32);
        rAh = *(const uint4*)(Agh + o);
        rBh = *(const uint4*)(Bgh + o); rBl = *(const uint4*)(Bgl + o);
      }
    }
    if (r < 7) { MFMA2(accE) } else { MFMA2(accH) }
  }

  __syncthreads();
  {
    const int r0 = wr*32 + ((lane>>4)<<2);
    const int c0 = wc*32 + (lane&15);
#pragma unroll
    for (int i = 0; i < 2; ++i)
#pragma unroll
      for (int j = 0; j < 2; ++j)
#pragma unroll
        for (int g = 0; g < 4; ++g) {
          fbuf[       kgw*4352 + (r0 + i*16 + g)*68 + c0 + j*16] = accE[i][j][g];
          fbuf[8704 + kgw*4352 + (r0 + i*16 + g)*68 + c0 + j*16] = accH[i][j][g];
        }
  }
  __syncthreads();
  const int erow = wave << 3;
  float eE[8], eH[8];
#pragma unroll
  for (int r = 0; r < 8; ++r) {
    eE[r] = fbuf[(erow+r)*68 + lane] + fbuf[4352 + (erow+r)*68 + lane];
    eH[r] = fbuf[8704 + (erow+r)*68 + lane] + fbuf[8704 + 4352 + (erow+r)*68 + lane];
  }

  const float alpha = __logf(1.f + __expf(alpha_u[0]));
  const float inv_s = 0.04419417382415922f;
  const float knl = rowscal[64 + lane], v2 = rowscal[192 + lane];
#pragma unroll
  for (int r = 0; r < 8; ++r) {
    const int s = mBase + erow + r;
    const float qns = rowscal[erow + r], u2 = rowscal[128 + erow + r];
    float de   = qns + knl - 2.f * eE[r];
    float dH   = eH[r];
    float Ac   = 1.f - 2.f*dH + v2;
    float Bc   = 1.f - u2;
    float num2 = Ac*Ac*u2 + Bc*Bc*v2 - 2.f*Ac*Bc*dH;
    float den  = fmaxf(1.f - 2.f*dH + u2*v2, 1e-5f);
    float frac = sqrtf(fmaxf(num2, 0.f)) * frcp(den);
    float nrm  = fminf(frac, 0.999f);
    float dh_  = __logf((1.f + nrm) * frcp(1.f - nrm));
    float dist = de + alpha * dh_ * dh_;
    float lg   = fminf(fmaxf(-dist * inv_s, -50.f), 0.f);
    float e    = __expf(lg);
    Eh[(size_t)s*S_LEN + nBase + lane] = bf16rne(e);
    float rs = wave_sum64(e);
    if (lane == 0) rowpart[s*16 + blockIdx.x] = rs;
  }
}

// ================= av2: out = diag(rinv) * (E @ voT^T) + bo =================
__global__ __launch_bounds__(512,4) void av2_mfma(
    const u16* __restrict__ Eh, const u16* __restrict__ voTh,
    const float* __restrict__ rowpart, const float* __restrict__ bo,
    float* __restrict__ out)
{
  __shared__ __align__(16) u16 stage[2][15360];
  __shared__ float rinvl[32];
  float* fbuf = (float*)stage;
  const int t = threadIdx.x, lane = t & 63, wave = t >> 6;
  const int mBase = blockIdx.y << 5, nBase = blockIdx.x << 6;
  if (t < 32) {
    float s_ = 0.f;
#pragma unroll
    for (int c = 0; c < 16; ++c) s_ += rowpart[(mBase+t)*16 + c];
    rinvl[t] = 1.f / s_;
  }
  const int kg = t >> 7, sub = t & 127;
  const int arow = sub >> 2, acol = (sub & 3) << 3;
  const int brow0 = sub >> 2, brow1 = 32 + (sub >> 2), bcol = (sub & 3) << 3;
  const int kgw = wave >> 1, wc = wave & 1;

  const u16* Ag = Eh   + (size_t)(mBase+arow)*S_LEN + kg*256 + acol;
  const u16* B0 = voTh + (size_t)(nBase+brow0)*S_LEN + kg*256 + bcol;
  const u16* B1 = voTh + (size_t)(nBase+brow1)*S_LEN + kg*256 + bcol;

  const int sA  = kg*3840 + arow*40 + acol;
  const int sB0 = kg*3840 + 1280 + brow0*40 + bcol;
  const int sB1 = kg*3840 + 1280 + brow1*40 + bcol;
  const int fa  = kgw*3840 + (lane&15)*40 + ((lane>>4)<<3);
  const int fb  = kgw*3840 + 1280 + (wc*32 + (lane&15))*40 + ((lane>>4)<<3);

  uint4 rA = *(const uint4*)Ag;
  uint4 rb0 = *(const uint4*)B0, rb1 = *(const uint4*)B1;
  *(uint4*)&stage[0][sA ] = rA;
  *(uint4*)&stage[0][sB0] = rb0; *(uint4*)&stage[0][sB1] = rb1;
  rA = *(const uint4*)(Ag + 32);
  rb0 = *(const uint4*)(B0 + 32); rb1 = *(const uint4*)(B1 + 32);

  f32x4 zero = {0.f,0.f,0.f,0.f};
  f32x4 acc[2][2] = {{zero,zero},{zero,zero}};
#pragma unroll
  for (int r = 0; r < 8; ++r) {
    __syncthreads();
    const u16* bufr = stage[r & 1];
    bf16x8 fAh[2], fBh[2];
#pragma unroll
    for (int i = 0; i < 2; ++i) {
      fAh[i] = *(const bf16x8*)&bufr[fa + i*640];
      fBh[i] = *(const bf16x8*)&bufr[fb + i*640];
    }
    if (r + 1 < 8) {
      u16* bufw = stage[(r + 1) & 1];
      *(uint4*)&bufw[sA ] = rA;
      *(uint4*)&bufw[sB0] = rb0; *(uint4*)&bufw[sB1] = rb1;
      if (r + 2 < 8) {
        const int o = (r + 2) * 32;
        rA = *(const uint4*)(Ag + o);
        rb0 = *(const uint4*)(B0 + o); rb1 = *(const uint4*)(B1 + o);
      }
    }
    MFMA1(acc);
  }

  __syncthreads();
  {
    const int r0 = (lane>>4)<<2;
    const int c0 = wc*32 + (lane&15);
#pragma unroll
    for (int i = 0; i < 2; ++i)
#pragma unroll
      for (int j = 0; j < 2; ++j)
#pragma unroll
        for (int g = 0; g < 4; ++g)
          fbuf[kgw*2176 + (r0 + i*16 + g)*68 + c0 + j*16] = acc[i][j][g];
  }
  __syncthreads();
  const int erow = wave << 2;
  const float b = bo[nBase + lane];
#pragma unroll
  for (int r = 0; r < 4; ++r) {
    const int row = erow + r;
    float e = fbuf[row*68 + lane] + fbuf[2176 + row*68 + lane]
            + fbuf[4352 + row*68 + lane] + fbuf[6528 + row*68 + lane];
    out[(size_t)(mBase+row)*D_TOT + nBase + lane] = e * rinvl[row] + b;
  }
}

extern "C" void kernel_launch(void* const* d_in, const int* in_sizes, int n_in,
                              void* d_out, int out_size, void* d_ws, size_t ws_size,
                              hipStream_t stream)
{
  const float* x   = (const float*)d_in[0];
  const float* wq  = (const float*)d_in[1];
  const float* bq  = (const float*)d_in[2];
  const float* wk  = (const float*)d_in[3];
  const float* bk  = (const float*)d_in[4];
  const float* wv  = (const float*)d_in[5];
  const float* bv  = (const float*)d_in[6];
  const float* wo  = (const float*)d_in[7];
  const float* bo  = (const float*)d_in[8];
  const float* alpha_u = (const float*)d_in[9];
  float* out = (float*)d_out;

  u16* U = (u16*)d_ws;
  u16* Qch   = U + 0;
  u16* Kch   = U + 524288;
  u16* Kcl   = U + 1048576;
  u16* voTh  = U + 1572864;
  u16* Eh    = U + 2097152;
  float* F = (float*)(U + 3145728);
  float* W2      = F;
  float* bvo     = F + 262144;
  float* qnpart  = F + 262656;
  float* knpart  = F + 270848;
  float* uh2a    = F + 279040;
  float* vh2a    = F + 280064;
  float* rowpart = F + 281088;

  wprod_mfma<<<dim3(8,8), 512, 0, stream>>>(wo, wv, bv, W2, bvo);
  qkv_mfma<<<dim3(8,16,3), 512, 0, stream>>>(x, wq,bq, wk,bk, W2, bvo,
      Qch, Kch, Kcl, voTh, qnpart, knpart, uh2a, vh2a);
  score_mfma<<<dim3(16,16), 512, 0, stream>>>(Qch, Kch, Kcl,
      qnpart, knpart, uh2a, vh2a, alpha_u, Eh, rowpart);
  av2_mfma<<<dim3(8,32), 512, 0, stream>>>(Eh, voTh, rowpart, bo, out);
}

// Round 12
// 46.799 us; speedup vs baseline: 1.0931x; 1.0931x over previous
//
#include <hip/hip_runtime.h>

#define S_LEN 1024
#define D_TOT 512
#define D_E   448

typedef short bf16x8 __attribute__((ext_vector_type(8)));
typedef float f32x4  __attribute__((ext_vector_type(4)));
typedef unsigned short u16;

__device__ __forceinline__ float frcp(float x) {
  float r; asm("v_rcp_f32 %0, %1" : "=v"(r) : "v"(x)); return r;
}

__device__ __forceinline__ float wave_sum64(float v) {
#pragma unroll
  for (int o = 32; o > 0; o >>= 1) v += __shfl_xor(v, o);
  return v;
}

__device__ __forceinline__ u16 bf16rne(float f) {
  unsigned u = __builtin_bit_cast(unsigned, f);
  return (u16)((u + 0x7fffu + ((u >> 16) & 1u)) >> 16);
}

__device__ __forceinline__ void bsplit(float f, u16 &h, u16 &l) {
  unsigned u  = __builtin_bit_cast(unsigned, f);
  unsigned ur = u + 0x7fffu + ((u >> 16) & 1u);
  h = (u16)(ur >> 16);
  float fh = __builtin_bit_cast(float, ur & 0xffff0000u);
  float r  = f - fh;
  l = bf16rne(r);
}

__device__ __forceinline__ void bsplit8(float4 a, float4 b, uint4 &h, uint4 &l) {
  u16 h0,h1,h2,h3,h4,h5,h6,h7, l0,l1,l2,l3,l4,l5,l6,l7;
  bsplit(a.x,h0,l0); bsplit(a.y,h1,l1); bsplit(a.z,h2,l2); bsplit(a.w,h3,l3);
  bsplit(b.x,h4,l4); bsplit(b.y,h5,l5); bsplit(b.z,h6,l6); bsplit(b.w,h7,l7);
  h.x = (unsigned)h0 | ((unsigned)h1<<16); h.y = (unsigned)h2 | ((unsigned)h3<<16);
  h.z = (unsigned)h4 | ((unsigned)h5<<16); h.w = (unsigned)h6 | ((unsigned)h7<<16);
  l.x = (unsigned)l0 | ((unsigned)l1<<16); l.y = (unsigned)l2 | ((unsigned)l3<<16);
  l.z = (unsigned)l4 | ((unsigned)l5<<16); l.w = (unsigned)l6 | ((unsigned)l7<<16);
}

__device__ __forceinline__ uint4 rne8(float4 a, float4 b) {
  uint4 h;
  h.x = (unsigned)bf16rne(a.x) | ((unsigned)bf16rne(a.y)<<16);
  h.y = (unsigned)bf16rne(a.z) | ((unsigned)bf16rne(a.w)<<16);
  h.z = (unsigned)bf16rne(b.x) | ((unsigned)bf16rne(b.y)<<16);
  h.w = (unsigned)bf16rne(b.z) | ((unsigned)bf16rne(b.w)<<16);
  return h;
}

#define MFMA2(ACC)                                                                              \
  _Pragma("unroll") for (int i_ = 0; i_ < 2; ++i_)                                              \
  _Pragma("unroll") for (int j_ = 0; j_ < 2; ++j_) {                                            \
    ACC[i_][j_] = __builtin_amdgcn_mfma_f32_16x16x32_bf16(fAh[i_], fBh[j_], ACC[i_][j_],0,0,0); \
    ACC[i_][j_] = __builtin_amdgcn_mfma_f32_16x16x32_bf16(fAh[i_], fBl[j_], ACC[i_][j_],0,0,0); \
  }

#define MFMA1(ACC)                                                                              \
  _Pragma("unroll") for (int i_ = 0; i_ < 2; ++i_)                                              \
  _Pragma("unroll") for (int j_ = 0; j_ < 2; ++j_)                                              \
    ACC[i_][j_] = __builtin_amdgcn_mfma_f32_16x16x32_bf16(fAh[i_], fBh[j_], ACC[i_][j_],0,0,0);

// ============ K1: blocks 0..255 -> q/k projections; 256..319 -> W2 = Wo@Wv, bvo = Wo@bv ============
__global__ __launch_bounds__(512,4) void k1_qk_wprod(
    const float* __restrict__ x,
    const float* __restrict__ wq, const float* __restrict__ bq,
    const float* __restrict__ wk, const float* __restrict__ bk,
    const float* __restrict__ wo, const float* __restrict__ wv,
    const float* __restrict__ bv,
    u16* __restrict__ Qch,
    u16* __restrict__ Kch, u16* __restrict__ Kcl,
    float* __restrict__ qnpart, float* __restrict__ knpart,
    float* __restrict__ uh2a, float* __restrict__ vh2a,
    float* __restrict__ W2, float* __restrict__ bvo)
{
  __shared__ __align__(16) char shm_[61440];
  u16* stg = (u16*)shm_;
  float* fbuf = (float*)shm_;
  const int bid = blockIdx.x;
  const int t = threadIdx.x, lane = t & 63, wave = t >> 6;
  const int kg = t >> 8, sub = t & 255;
  const int srow = sub >> 2, scol = (sub & 3) << 3;
  const int kgw = wave >> 2, wr = (wave >> 1) & 1, wc = wave & 1;

  if (bid < 256) {
    // ---------------- q/k projection ----------------
    const int z   = bid >> 7;           // 0 -> q, 1 -> k
    const int rem = bid & 127;
    const int mBase = (rem >> 3) << 6, nx = rem & 7, nBase = nx << 6;
    const float* W = z ? wk : wq;
    const float* bias = z ? bk : bq;

    const float* Ag = x + (size_t)(mBase + srow) * D_TOT + scol + kg * 256;
    const float* Bg = W + (size_t)(nBase + srow) * D_TOT + scol + kg * 256;

    const int sb = kg * 7680 + srow * 40 + scol;
    const int fa = kgw * 7680 + (wr * 32 + (lane & 15)) * 40 + ((lane >> 4) << 3);
    const int fb = kgw * 7680 + 2560 + (wc * 32 + (lane & 15)) * 40 + ((lane >> 4) << 3);

    float4 a0 = *(const float4*)Ag, a1 = *(const float4*)(Ag + 4);
    float4 b0 = *(const float4*)Bg, b1 = *(const float4*)(Bg + 4);
    {
      uint4 hB,lB; bsplit8(b0,b1,hB,lB);
      *(uint4*)&stg[sb       ] = rne8(a0,a1);
      *(uint4*)&stg[sb + 2560] = hB;
      *(uint4*)&stg[sb + 5120] = lB;
    }
    a0 = *(const float4*)(Ag + 32); a1 = *(const float4*)(Ag + 36);
    b0 = *(const float4*)(Bg + 32); b1 = *(const float4*)(Bg + 36);

    f32x4 zero = {0.f,0.f,0.f,0.f};
    f32x4 acc[2][2] = {{zero,zero},{zero,zero}};
#pragma unroll
    for (int r = 0; r < 8; ++r) {
      __syncthreads();
      const u16* bufr = stg + (r & 1) * 15360;
      bf16x8 fAh[2], fBh[2], fBl[2];
#pragma unroll
      for (int i = 0; i < 2; ++i) {
        fAh[i] = *(const bf16x8*)&bufr[fa        + i*640];
        fBh[i] = *(const bf16x8*)&bufr[fb        + i*640];
        fBl[i] = *(const bf16x8*)&bufr[fb + 2560 + i*640];
      }
      if (r + 1 < 8) {
        u16* bufw = stg + ((r + 1) & 1) * 15360;
        uint4 hB,lB; bsplit8(b0,b1,hB,lB);
        *(uint4*)&bufw[sb       ] = rne8(a0,a1);
        *(uint4*)&bufw[sb + 2560] = hB;
        *(uint4*)&bufw[sb + 5120] = lB;
        if (r + 2 < 8) {
          const int o = (r + 2) * 32;
          a0 = *(const float4*)(Ag + o); a1 = *(const float4*)(Ag + o + 4);
          b0 = *(const float4*)(Bg + o); b1 = *(const float4*)(Bg + o + 4);
        }
      }
      MFMA2(acc);
    }

    __syncthreads();
    {
      const int r0 = wr*32 + ((lane>>4)<<2);
      const int c0 = wc*32 + (lane&15);
#pragma unroll
      for (int i = 0; i < 2; ++i)
#pragma unroll
        for (int j = 0; j < 2; ++j)
#pragma unroll
          for (int g = 0; g < 4; ++g)
            fbuf[kgw*4352 + (r0 + i*16 + g)*68 + c0 + j*16] = acc[i][j][g];
    }
    __syncthreads();
    const int erow = wave << 3;
    float val[8];
    {
      const float b = bias[nBase + lane];
#pragma unroll
      for (int r = 0; r < 8; ++r)
        val[r] = fbuf[(erow+r)*68 + lane] + fbuf[4352 + (erow+r)*68 + lane] + b;
    }

    u16* Ch = z ? Kch : Qch;
    float* np_ = z ? knpart : qnpart;
    float* u2a = z ? vh2a  : uh2a;
    if (nx < 7) {
#pragma unroll
      for (int r = 0; r < 8; ++r) {
        const int s = mBase + erow + r;
        if (z) {
          u16 h,l; bsplit(val[r],h,l);
          Kch[(size_t)s*D_TOT + nBase + lane] = h;
          Kcl[(size_t)s*D_TOT + nBase + lane] = l;
        } else {
          Qch[(size_t)s*D_TOT + nBase + lane] = bf16rne(val[r]);
        }
        float p = wave_sum64(val[r]*val[r]);
        if (lane == 0) np_[s*8 + nx] = p;
      }
    } else {
#pragma unroll
      for (int r = 0; r < 8; ++r) {
        const int s = mBase + erow + r;
        float n2 = wave_sum64(val[r]*val[r]);
        float nn = sqrtf(n2);
        float n  = fmaxf(nn, 1e-5f);
        float e2n = __expf(2.f*n);
        float th  = 1.f - 2.f*frcp(e2n + 1.f);
        float rn  = frcp(n);
        float pn  = th * nn * rn;
        float scale = fminf(0.999f * frcp(fmaxf(pn, 1e-5f)), 1.f);
        float u = th * rn * scale * val[r];
        float un = pn * scale;
        if (z) {
          u16 h,l; bsplit(u,h,l);
          Kch[(size_t)s*D_TOT + nBase + lane] = h;
          Kcl[(size_t)s*D_TOT + nBase + lane] = l;
        } else {
          Qch[(size_t)s*D_TOT + nBase + lane] = bf16rne(u);
        }
        if (lane == 0) u2a[s] = un*un;
      }
    }
  } else {
    // ---------------- wprod: W2 = Wo @ Wv, bvo = Wo @ bv ----------------
    const int b2 = bid - 256;
    const int mBase = (b2 >> 3) << 6, nx = b2 & 7, nBase = nx << 6;

    const float* Ag = wo + (size_t)(mBase + srow) * D_TOT + kg * 256 + scol;
    const int bk_ = sub & 31, bng = sub >> 5;
    const float* Bg = wv + (size_t)(kg * 256 + bk_) * D_TOT + nBase + bng * 8;

    const int sA  = kg * 7680 + srow * 40 + scol;
    const int sBh = kg * 7680 + 2560;
    const int sBl = kg * 7680 + 5120;
    const int fa  = kgw * 7680 + (wr * 32 + (lane & 15)) * 40 + ((lane >> 4) << 3);
    const int fbh = kgw * 7680 + 2560 + (wc * 32 + (lane & 15)) * 40 + ((lane >> 4) << 3);

    f32x4 zero = {0.f,0.f,0.f,0.f};
    f32x4 acc[2][2] = {{zero,zero},{zero,zero}};
#pragma unroll
    for (int r = 0; r < 8; ++r) {
      float4 a0 = *(const float4*)(Ag + r*32);
      float4 a1 = *(const float4*)(Ag + r*32 + 4);
      float4 w0 = *(const float4*)(Bg + (size_t)r*32*D_TOT);
      float4 w1 = *(const float4*)(Bg + (size_t)r*32*D_TOT + 4);
      __syncthreads();
      *(uint4*)&stg[sA] = rne8(a0, a1);
      float bb[8] = {w0.x,w0.y,w0.z,w0.w,w1.x,w1.y,w1.z,w1.w};
#pragma unroll
      for (int j = 0; j < 8; ++j) {
        u16 h,l; bsplit(bb[j], h, l);
        stg[sBh + (bng*8 + j)*40 + bk_] = h;
        stg[sBl + (bng*8 + j)*40 + bk_] = l;
      }
      __syncthreads();
      bf16x8 fAh[2], fBh[2], fBl[2];
#pragma unroll
      for (int i = 0; i < 2; ++i) {
        fAh[i] = *(const bf16x8*)&stg[fa         + i*640];
        fBh[i] = *(const bf16x8*)&stg[fbh        + i*640];
        fBl[i] = *(const bf16x8*)&stg[fbh + 2560 + i*640];
      }
      MFMA2(acc);
    }

    __syncthreads();
    {
      const int r0 = wr*32 + ((lane>>4)<<2);
      const int c0 = wc*32 + (lane&15);
#pragma unroll
      for (int i = 0; i < 2; ++i)
#pragma unroll
        for (int j = 0; j < 2; ++j)
#pragma unroll
          for (int g = 0; g < 4; ++g)
            fbuf[kgw*4352 + (r0 + i*16 + g)*68 + c0 + j*16] = acc[i][j][g];
    }
    __syncthreads();
    const int erow = wave << 3;
#pragma unroll
    for (int r = 0; r < 8; ++r) {
      float v = fbuf[(erow+r)*68 + lane] + fbuf[4352 + (erow+r)*68 + lane];
      W2[(size_t)(mBase + erow + r)*D_TOT + nBase + lane] = v;
    }

    if (nx == 0) {
      __syncthreads();
      const int m = t >> 3, sl = t & 7;
      const float* wrow = wo + (size_t)(mBase + m)*D_TOT + sl*64;
      float s_ = 0.f;
#pragma unroll
      for (int k = 0; k < 64; ++k) s_ += wrow[k] * bv[sl*64 + k];
      fbuf[m*8 + sl] = s_;
      __syncthreads();
      if (t < 64) {
        float s2 = 0.f;
#pragma unroll
        for (int c = 0; c < 8; ++c) s2 += fbuf[t*8 + c];
        bvo[mBase + t] = s2;
      }
    }
  }
}

// ============ K2: blocks 0..255 -> score; 256..383 -> vo = x@W2.T + bvo (transposed, hi-only) ============
__global__ __launch_bounds__(512,4) void k2_score_vo(
    const float* __restrict__ x,
    const u16* __restrict__ Qch,
    const u16* __restrict__ Kch, const u16* __restrict__ Kcl,
    const float* __restrict__ qnpart, const float* __restrict__ knpart,
    const float* __restrict__ uh2a, const float* __restrict__ vh2a,
    const float* __restrict__ alpha_u,
    const float* __restrict__ w2, const float* __restrict__ bvo,
    u16* __restrict__ Eh, float* __restrict__ rowpart,
    u16* __restrict__ voTh)
{
  __shared__ __align__(16) char shm_[69632];
  __shared__ float rowscal[256];
  u16* stg = (u16*)shm_;
  float* fbuf = (float*)shm_;
  const int bid = blockIdx.x;
  const int t = threadIdx.x, lane = t & 63, wave = t >> 6;
  const int kg = t >> 8, sub = t & 255;
  const int srow = sub >> 2, scol = (sub & 3) << 3;
  const int kgw = wave >> 2, wr = (wave >> 1) & 1, wc = wave & 1;

  if (bid < 256) {
    // ---------------- score ----------------
    const int nx = bid & 15;
    const int mBase = (bid >> 4) << 6, nBase = nx << 6;
    if (t < 64) {
      float s_ = 0.f;
#pragma unroll
      for (int c = 0; c < 7; ++c) s_ += qnpart[(mBase+t)*8 + c];
      rowscal[t] = s_;
    } else if (t < 128) {
      float s_ = 0.f;
#pragma unroll
      for (int c = 0; c < 7; ++c) s_ += knpart[(nBase+t-64)*8 + c];
      rowscal[t] = s_;
    } else if (t < 192) rowscal[t] = uh2a[mBase + t - 128];
    else if (t < 256)   rowscal[t] = vh2a[nBase + t - 192];

    const u16* Agh = Qch + (size_t)(mBase+srow)*D_TOT + scol;
    const u16* Bgh = Kch + (size_t)(nBase+srow)*D_TOT + scol;
    const u16* Bgl = Kcl + (size_t)(nBase+srow)*D_TOT + scol;

    const int sb  = kg * 7680 + srow * 40 + scol;
    const int fa  = kgw * 7680 + (wr * 32 + (lane & 15)) * 40 + ((lane >> 4) << 3);
    const int fbh = kgw * 7680 + 2560 + (wc * 32 + (lane & 15)) * 40 + ((lane >> 4) << 3);

    int kb = kg * 224;
    uint4 rAh = *(const uint4*)(Agh + kb);
    uint4 rBh = *(const uint4*)(Bgh + kb), rBl = *(const uint4*)(Bgl + kb);
    *(uint4*)&stg[sb       ] = rAh;
    *(uint4*)&stg[sb + 2560] = rBh;
    *(uint4*)&stg[sb + 5120] = rBl;
    kb = kg * 224 + 32;
    rAh = *(const uint4*)(Agh + kb);
    rBh = *(const uint4*)(Bgh + kb); rBl = *(const uint4*)(Bgl + kb);

    f32x4 zero = {0.f,0.f,0.f,0.f};
    f32x4 accE[2][2] = {{zero,zero},{zero,zero}};
    f32x4 accH[2][2] = {{zero,zero},{zero,zero}};
#pragma unroll
    for (int r = 0; r < 8; ++r) {
      __syncthreads();
      const u16* bufr = stg + (r & 1) * 15360;
      bf16x8 fAh[2], fBh[2], fBl[2];
#pragma unroll
      for (int i = 0; i < 2; ++i) {
        fAh[i] = *(const bf16x8*)&bufr[fa         + i*640];
        fBh[i] = *(const bf16x8*)&bufr[fbh        + i*640];
        fBl[i] = *(const bf16x8*)&bufr[fbh + 2560 + i*640];
      }
      if (r + 1 < 8) {
        u16* bufw = stg + ((r + 1) & 1) * 15360;
        *(uint4*)&bufw[sb       ] = rAh;
        *(uint4*)&bufw[sb + 2560] = rBh;
        *(uint4*)&bufw[sb + 5120] = rBl;
        if (r + 2 < 8) {
          const int o = (r + 2 < 7) ? (kg*224 + (r+2)*32) : (448 + kg*32);
          rAh = *(const uint4*)(Agh + o);
          rBh = *(const uint4*)(Bgh + o); rBl = *(const uint4*)(Bgl + o);
        }
      }
      if (r < 7) { MFMA2(accE) } else { MFMA2(accH) }
    }

    __syncthreads();
    {
      const int r0 = wr*32 + ((lane>>4)<<2);
      const int c0 = wc*32 + (lane&15);
#pragma unroll
      for (int i = 0; i < 2; ++i)
#pragma unroll
        for (int j = 0; j < 2; ++j)
#pragma unroll
          for (int g = 0; g < 4; ++g) {
            fbuf[       kgw*4352 + (r0 + i*16 + g)*68 + c0 + j*16] = accE[i][j][g];
            fbuf[8704 + kgw*4352 + (r0 + i*16 + g)*68 + c0 + j*16] = accH[i][j][g];
          }
    }
    __syncthreads();
    const int erow = wave << 3;
    float eE[8], eH[8];
#pragma unroll
    for (int r = 0; r < 8; ++r) {
      eE[r] = fbuf[(erow+r)*68 + lane] + fbuf[4352 + (erow+r)*68 + lane];
      eH[r] = fbuf[8704 + (erow+r)*68 + lane] + fbuf[8704 + 4352 + (erow+r)*68 + lane];
    }

    const float alpha = __logf(1.f + __expf(alpha_u[0]));
    const float inv_s = 0.04419417382415922f;
    const float knl = rowscal[64 + lane], v2 = rowscal[192 + lane];
#pragma unroll
    for (int r = 0; r < 8; ++r) {
      const int s = mBase + erow + r;
      const float qns = rowscal[erow + r], u2 = rowscal[128 + erow + r];
      float de   = qns + knl - 2.f * eE[r];
      float dH   = eH[r];
      float Ac   = 1.f - 2.f*dH + v2;
      float Bc   = 1.f - u2;
      float num2 = Ac*Ac*u2 + Bc*Bc*v2 - 2.f*Ac*Bc*dH;
      float den  = fmaxf(1.f - 2.f*dH + u2*v2, 1e-5f);
      float frac = sqrtf(fmaxf(num2, 0.f)) * frcp(den);
      float nrm  = fminf(frac, 0.999f);
      float dh_  = __logf((1.f + nrm) * frcp(1.f - nrm));
      float dist = de + alpha * dh_ * dh_;
      float lg   = fminf(fmaxf(-dist * inv_s, -50.f), 0.f);
      float e    = __expf(lg);
      Eh[(size_t)s*S_LEN + nBase + lane] = bf16rne(e);
      float rs = wave_sum64(e);
      if (lane == 0) rowpart[s*16 + nx] = rs;
    }
  } else {
    // ---------------- vo = x @ W2.T + bvo, stored transposed hi-only ----------------
    const int b2 = bid - 256;
    const int mBase = (b2 >> 3) << 6, nBase = (b2 & 7) << 6;

    const float* Ag = x  + (size_t)(mBase + srow) * D_TOT + scol + kg * 256;
    const float* Bg = w2 + (size_t)(nBase + srow) * D_TOT + scol + kg * 256;

    const int sb = kg * 7680 + srow * 40 + scol;
    const int fa = kgw * 7680 + (wr * 32 + (lane & 15)) * 40 + ((lane >> 4) << 3);
    const int fb = kgw * 7680 + 2560 + (wc * 32 + (lane & 15)) * 40 + ((lane >> 4) << 3);

    float4 a0 = *(const float4*)Ag, a1 = *(const float4*)(Ag + 4);
    float4 b0 = *(const float4*)Bg, b1 = *(const float4*)(Bg + 4);
    {
      uint4 hB,lB; bsplit8(b0,b1,hB,lB);
      *(uint4*)&stg[sb       ] = rne8(a0,a1);
      *(uint4*)&stg[sb + 2560] = hB;
      *(uint4*)&stg[sb + 5120] = lB;
    }
    a0 = *(const float4*)(Ag + 32); a1 = *(const float4*)(Ag + 36);
    b0 = *(const float4*)(Bg + 32); b1 = *(const float4*)(Bg + 36);

    f32x4 zero = {0.f,0.f,0.f,0.f};
    f32x4 acc[2][2] = {{zero,zero},{zero,zero}};
#pragma unroll
    for (int r = 0; r < 8; ++r) {
      __syncthreads();
      const u16* bufr = stg + (r & 1) * 15360;
      bf16x8 fAh[2], fBh[2], fBl[2];
#pragma unroll
      for (int i = 0; i < 2; ++i) {
        fAh[i] = *(const bf16x8*)&bufr[fa        + i*640];
        fBh[i] = *(const bf16x8*)&bufr[fb        + i*640];
        fBl[i] = *(const bf16x8*)&bufr[fb + 2560 + i*640];
      }
      if (r + 1 < 8) {
        u16* bufw = stg + ((r + 1) & 1) * 15360;
        uint4 hB,lB; bsplit8(b0,b1,hB,lB);
        *(uint4*)&bufw[sb       ] = rne8(a0,a1);
        *(uint4*)&bufw[sb + 2560] = hB;
        *(uint4*)&bufw[sb + 5120] = lB;
        if (r + 2 < 8) {
          const int o = (r + 2) * 32;
          a0 = *(const float4*)(Ag + o); a1 = *(const float4*)(Ag + o + 4);
          b0 = *(const float4*)(Bg + o); b1 = *(const float4*)(Bg + o + 4);
        }
      }
      MFMA2(acc);
    }

    __syncthreads();
    {
      const int r0 = wr*32 + ((lane>>4)<<2);
      const int c0 = wc*32 + (lane&15);
#pragma unroll
      for (int i = 0; i < 2; ++i)
#pragma unroll
        for (int j = 0; j < 2; ++j)
#pragma unroll
          for (int g = 0; g < 4; ++g)
            fbuf[kgw*4352 + (r0 + i*16 + g)*68 + c0 + j*16] = acc[i][j][g];
    }
    __syncthreads();
    const int erow = wave << 3;
    u16 hh[8];
    {
      const float b = bvo[nBase + lane];
#pragma unroll
      for (int r = 0; r < 8; ++r)
        hh[r] = bf16rne(fbuf[(erow+r)*68 + lane] + fbuf[4352 + (erow+r)*68 + lane] + b);
    }
    const size_t off = (size_t)(nBase + lane) * S_LEN + mBase + erow;
    ushort4 p0{hh[0],hh[1],hh[2],hh[3]}, p1{hh[4],hh[5],hh[6],hh[7]};
    *(ushort4*)(voTh + off) = p0; *(ushort4*)(voTh + off + 4) = p1;
  }
}

// ============ K3: out = diag(rinv) * (E @ voT^T) + bo ============
__global__ __launch_bounds__(512,4) void av2_mfma(
    const u16* __restrict__ Eh, const u16* __restrict__ voTh,
    const float* __restrict__ rowpart, const float* __restrict__ bo,
    float* __restrict__ out)
{
  __shared__ __align__(16) u16 stage[2][15360];
  __shared__ float rinvl[32];
  float* fbuf = (float*)stage;
  const int t = threadIdx.x, lane = t & 63, wave = t >> 6;
  const int mBase = blockIdx.y << 5, nBase = blockIdx.x << 6;
  if (t < 32) {
    float s_ = 0.f;
#pragma unroll
    for (int c = 0; c < 16; ++c) s_ += rowpart[(mBase+t)*16 + c];
    rinvl[t] = 1.f / s_;
  }
  const int kg = t >> 7, sub = t & 127;
  const int arow = sub >> 2, acol = (sub & 3) << 3;
  const int brow0 = sub >> 2, brow1 = 32 + (sub >> 2), bcol = (sub & 3) << 3;
  const int kgw = wave >> 1, wc = wave & 1;

  const u16* Ag = Eh   + (size_t)(mBase+arow)*S_LEN + kg*256 + acol;
  const u16* B0 = voTh + (size_t)(nBase+brow0)*S_LEN + kg*256 + bcol;
  const u16* B1 = voTh + (size_t)(nBase+brow1)*S_LEN + kg*256 + bcol;

  const int sA  = kg*3840 + arow*40 + acol;
  const int sB0 = kg*3840 + 1280 + brow0*40 + bcol;
  const int sB1 = kg*3840 + 1280 + brow1*40 + bcol;
  const int fa  = kgw*3840 + (lane&15)*40 + ((lane>>4)<<3);
  const int fb  = kgw*3840 + 1280 + (wc*32 + (lane&15))*40 + ((lane>>4)<<3);

  uint4 rA = *(const uint4*)Ag;
  uint4 rb0 = *(const uint4*)B0, rb1 = *(const uint4*)B1;
  *(uint4*)&stage[0][sA ] = rA;
  *(uint4*)&stage[0][sB0] = rb0; *(uint4*)&stage[0][sB1] = rb1;
  rA = *(const uint4*)(Ag + 32);
  rb0 = *(const uint4*)(B0 + 32); rb1 = *(const uint4*)(B1 + 32);

  f32x4 zero = {0.f,0.f,0.f,0.f};
  f32x4 acc[2][2] = {{zero,zero},{zero,zero}};
#pragma unroll
  for (int r = 0; r < 8; ++r) {
    __syncthreads();
    const u16* bufr = stage[r & 1];
    bf16x8 fAh[2], fBh[2];
#pragma unroll
    for (int i = 0; i < 2; ++i) {
      fAh[i] = *(const bf16x8*)&bufr[fa + i*640];
      fBh[i] = *(const bf16x8*)&bufr[fb + i*640];
    }
    if (r + 1 < 8) {
      u16* bufw = stage[(r + 1) & 1];
      *(uint4*)&bufw[sA ] = rA;
      *(uint4*)&bufw[sB0] = rb0; *(uint4*)&bufw[sB1] = rb1;
      if (r + 2 < 8) {
        const int o = (r + 2) * 32;
        rA = *(const uint4*)(Ag + o);
        rb0 = *(const uint4*)(B0 + o); rb1 = *(const uint4*)(B1 + o);
      }
    }
    MFMA1(acc);
  }

  __syncthreads();
  {
    const int r0 = (lane>>4)<<2;
    const int c0 = wc*32 + (lane&15);
#pragma unroll
    for (int i = 0; i < 2; ++i)
#pragma unroll
      for (int j = 0; j < 2; ++j)
#pragma unroll
        for (int g = 0; g < 4; ++g)
          fbuf[kgw*2176 + (r0 + i*16 + g)*68 + c0 + j*16] = acc[i][j][g];
  }
  __syncthreads();
  const int erow = wave << 2;
  const float b = bo[nBase + lane];
#pragma unroll
  for (int r = 0; r < 4; ++r) {
    const int row = erow + r;
    float e = fbuf[row*68 + lane] + fbuf[2176 + row*68 + lane]
            + fbuf[4352 + row*68 + lane] + fbuf[6528 + row*68 + lane];
    out[(size_t)(mBase+row)*D_TOT + nBase + lane] = e * rinvl[row] + b;
  }
}

extern "C" void kernel_launch(void* const* d_in, const int* in_sizes, int n_in,
                              void* d_out, int out_size, void* d_ws, size_t ws_size,
                              hipStream_t stream)
{
  const float* x   = (const float*)d_in[0];
  const float* wq  = (const float*)d_in[1];
  const float* bq  = (const float*)d_in[2];
  const float* wk  = (const float*)d_in[3];
  const float* bk  = (const float*)d_in[4];
  const float* wv  = (const float*)d_in[5];
  const float* bv  = (const float*)d_in[6];
  const float* wo  = (const float*)d_in[7];
  const float* bo  = (const float*)d_in[8];
  const float* alpha_u = (const float*)d_in[9];
  float* out = (float*)d_out;

  u16* U = (u16*)d_ws;
  u16* Qch   = U + 0;
  u16* Kch   = U + 524288;
  u16* Kcl   = U + 1048576;
  u16* voTh  = U + 1572864;
  u16* Eh    = U + 2097152;
  float* F = (float*)(U + 3145728);
  float* W2      = F;
  float* bvo     = F + 262144;
  float* qnpart  = F + 262656;
  float* knpart  = F + 270848;
  float* uh2a    = F + 279040;
  float* vh2a    = F + 280064;
  float* rowpart = F + 281088;

  k1_qk_wprod<<<dim3(320), 512, 0, stream>>>(x, wq, bq, wk, bk, wo, wv, bv,
      Qch, Kch, Kcl, qnpart, knpart, uh2a, vh2a, W2, bvo);
  k2_score_vo<<<dim3(384), 512, 0, stream>>>(x, Qch, Kch, Kcl,
      qnpart, knpart, uh2a, vh2a, alpha_u, W2, bvo, Eh, rowpart, voTh);
  av2_mfma<<<dim3(8,32), 512, 0, stream>>>(Eh, voTh, rowpart, bo, out);
}

// Round 13
// 43.912 us; speedup vs baseline: 1.1650x; 1.0657x over previous
//
#include <hip/hip_runtime.h>

#define S_LEN 1024
#define D_TOT 512
#define D_E   448

typedef short bf16x8 __attribute__((ext_vector_type(8)));
typedef float f32x4  __attribute__((ext_vector_type(4)));
typedef unsigned short u16;

__device__ __forceinline__ float frcp(float x) {
  float r; asm("v_rcp_f32 %0, %1" : "=v"(r) : "v"(x)); return r;
}

__device__ __forceinline__ float wave_sum64(float v) {
#pragma unroll
  for (int o = 32; o > 0; o >>= 1) v += __shfl_xor(v, o);
  return v;
}

__device__ __forceinline__ u16 bf16rne(float f) {
  unsigned u = __builtin_bit_cast(unsigned, f);
  return (u16)((u + 0x7fffu + ((u >> 16) & 1u)) >> 16);
}

__device__ __forceinline__ void bsplit(float f, u16 &h, u16 &l) {
  unsigned u  = __builtin_bit_cast(unsigned, f);
  unsigned ur = u + 0x7fffu + ((u >> 16) & 1u);
  h = (u16)(ur >> 16);
  float fh = __builtin_bit_cast(float, ur & 0xffff0000u);
  float r  = f - fh;
  l = bf16rne(r);
}

__device__ __forceinline__ void bsplit8(float4 a, float4 b, uint4 &h, uint4 &l) {
  u16 h0,h1,h2,h3,h4,h5,h6,h7, l0,l1,l2,l3,l4,l5,l6,l7;
  bsplit(a.x,h0,l0); bsplit(a.y,h1,l1); bsplit(a.z,h2,l2); bsplit(a.w,h3,l3);
  bsplit(b.x,h4,l4); bsplit(b.y,h5,l5); bsplit(b.z,h6,l6); bsplit(b.w,h7,l7);
  h.x = (unsigned)h0 | ((unsigned)h1<<16); h.y = (unsigned)h2 | ((unsigned)h3<<16);
  h.z = (unsigned)h4 | ((unsigned)h5<<16); h.w = (unsigned)h6 | ((unsigned)h7<<16);
  l.x = (unsigned)l0 | ((unsigned)l1<<16); l.y = (unsigned)l2 | ((unsigned)l3<<16);
  l.z = (unsigned)l4 | ((unsigned)l5<<16); l.w = (unsigned)l6 | ((unsigned)l7<<16);
}

__device__ __forceinline__ uint4 rne8(float4 a, float4 b) {
  uint4 h;
  h.x = (unsigned)bf16rne(a.x) | ((unsigned)bf16rne(a.y)<<16);
  h.y = (unsigned)bf16rne(a.z) | ((unsigned)bf16rne(a.w)<<16);
  h.z = (unsigned)bf16rne(b.x) | ((unsigned)bf16rne(b.y)<<16);
  h.w = (unsigned)bf16rne(b.z) | ((unsigned)bf16rne(b.w)<<16);
  return h;
}

#define MFMA2(ACC)                                                                              \
  _Pragma("unroll") for (int i_ = 0; i_ < 2; ++i_)                                              \
  _Pragma("unroll") for (int j_ = 0; j_ < 2; ++j_) {                                            \
    ACC[i_][j_] = __builtin_amdgcn_mfma_f32_16x16x32_bf16(fAh[i_], fBh[j_], ACC[i_][j_],0,0,0); \
    ACC[i_][j_] = __builtin_amdgcn_mfma_f32_16x16x32_bf16(fAh[i_], fBl[j_], ACC[i_][j_],0,0,0); \
  }

// ================= QKV (round-8 verbatim): q/k/v = x @ W.T + b =================
__global__ __launch_bounds__(512,4) void qkv_mfma(
    const float* __restrict__ x,
    const float* __restrict__ wq, const float* __restrict__ bq,
    const float* __restrict__ wk, const float* __restrict__ bk,
    const float* __restrict__ wv, const float* __restrict__ bv,
    u16* __restrict__ Qch,
    u16* __restrict__ Kch, u16* __restrict__ Kcl,
    u16* __restrict__ vTh, u16* __restrict__ vTl,
    float* __restrict__ qnpart, float* __restrict__ knpart,
    float* __restrict__ uh2a, float* __restrict__ vh2a)
{
  __shared__ __align__(16) u16 stage[2][15360];
  float* fbuf = (float*)stage;
  const int z = blockIdx.z;
  const float* W; const float* bias;
  if (z == 0)      { W = wq; bias = bq; }
  else if (z == 1) { W = wk; bias = bk; }
  else             { W = wv; bias = bv; }
  const int mBase = blockIdx.y << 6, nBase = blockIdx.x << 6;
  const int t = threadIdx.x, lane = t & 63, wave = t >> 6;
  const int kg = t >> 8, sub = t & 255;
  const int srow = sub >> 2, scol = (sub & 3) << 3;
  const int kgw = wave >> 2, wr = (wave >> 1) & 1, wc = wave & 1;

  const float* Ag = x + (size_t)(mBase + srow) * D_TOT + scol + kg * 256;
  const float* Bg = W + (size_t)(nBase + srow) * D_TOT + scol + kg * 256;

  const int sb = kg * 7680 + srow * 40 + scol;
  const int fa = kgw * 7680 + (wr * 32 + (lane & 15)) * 40 + ((lane >> 4) << 3);
  const int fb = kgw * 7680 + 2560 + (wc * 32 + (lane & 15)) * 40 + ((lane >> 4) << 3);

  float4 a0 = *(const float4*)Ag, a1 = *(const float4*)(Ag + 4);
  float4 b0 = *(const float4*)Bg, b1 = *(const float4*)(Bg + 4);
  {
    uint4 hB,lB; bsplit8(b0,b1,hB,lB);
    *(uint4*)&stage[0][sb       ] = rne8(a0,a1);
    *(uint4*)&stage[0][sb + 2560] = hB;
    *(uint4*)&stage[0][sb + 5120] = lB;
  }
  a0 = *(const float4*)(Ag + 32); a1 = *(const float4*)(Ag + 36);
  b0 = *(const float4*)(Bg + 32); b1 = *(const float4*)(Bg + 36);

  f32x4 zero = {0.f,0.f,0.f,0.f};
  f32x4 acc[2][2] = {{zero,zero},{zero,zero}};
#pragma unroll
  for (int r = 0; r < 8; ++r) {
    __syncthreads();
    const u16* bufr = stage[r & 1];
    bf16x8 fAh[2], fBh[2], fBl[2];
#pragma unroll
    for (int i = 0; i < 2; ++i) {
      fAh[i] = *(const bf16x8*)&bufr[fa        + i*640];
      fBh[i] = *(const bf16x8*)&bufr[fb        + i*640];
      fBl[i] = *(const bf16x8*)&bufr[fb + 2560 + i*640];
    }
    if (r + 1 < 8) {
      u16* bufw = stage[(r + 1) & 1];
      uint4 hB,lB; bsplit8(b0,b1,hB,lB);
      *(uint4*)&bufw[sb       ] = rne8(a0,a1);
      *(uint4*)&bufw[sb + 2560] = hB;
      *(uint4*)&bufw[sb + 5120] = lB;
      if (r + 2 < 8) {
        const int o = (r + 2) * 32;
        a0 = *(const float4*)(Ag + o); a1 = *(const float4*)(Ag + o + 4);
        b0 = *(const float4*)(Bg + o); b1 = *(const float4*)(Bg + o + 4);
      }
    }
    MFMA2(acc);
  }

  __syncthreads();
  {
    const int r0 = wr*32 + ((lane>>4)<<2);
    const int c0 = wc*32 + (lane&15);
#pragma unroll
    for (int i = 0; i < 2; ++i)
#pragma unroll
      for (int j = 0; j < 2; ++j)
#pragma unroll
        for (int g = 0; g < 4; ++g)
          fbuf[kgw*4352 + (r0 + i*16 + g)*68 + c0 + j*16] = acc[i][j][g];
  }
  __syncthreads();
  const int erow = wave << 3;
  float val[8];
  {
    const float b = bias[nBase + lane];
#pragma unroll
    for (int r = 0; r < 8; ++r)
      val[r] = fbuf[(erow+r)*68 + lane] + fbuf[4352 + (erow+r)*68 + lane] + b;
  }

  if (z == 2) {
    u16 hh[8], ll[8];
#pragma unroll
    for (int r = 0; r < 8; ++r) bsplit(val[r], hh[r], ll[r]);
    const size_t off = (size_t)(nBase + lane) * S_LEN + mBase + erow;
    ushort4 p0{hh[0],hh[1],hh[2],hh[3]}, p1{hh[4],hh[5],hh[6],hh[7]};
    ushort4 q0{ll[0],ll[1],ll[2],ll[3]}, q1{ll[4],ll[5],ll[6],ll[7]};
    *(ushort4*)(vTh + off) = p0; *(ushort4*)(vTh + off + 4) = p1;
    *(ushort4*)(vTl + off) = q0; *(ushort4*)(vTl + off + 4) = q1;
  } else if (z == 1) {
    if (blockIdx.x < 7) {
#pragma unroll
      for (int r = 0; r < 8; ++r) {
        const int s = mBase + erow + r;
        u16 h,l; bsplit(val[r],h,l);
        Kch[(size_t)s*D_TOT + nBase + lane] = h;
        Kcl[(size_t)s*D_TOT + nBase + lane] = l;
        float p = wave_sum64(val[r]*val[r]);
        if (lane == 0) knpart[s*8 + blockIdx.x] = p;
      }
    } else {
#pragma unroll
      for (int r = 0; r < 8; ++r) {
        const int s = mBase + erow + r;
        float n2 = wave_sum64(val[r]*val[r]);
        float nn = sqrtf(n2);
        float n  = fmaxf(nn, 1e-5f);
        float e2n = __expf(2.f*n);
        float th  = 1.f - 2.f*frcp(e2n + 1.f);
        float rn  = frcp(n);
        float pn  = th * nn * rn;
        float scale = fminf(0.999f * frcp(fmaxf(pn, 1e-5f)), 1.f);
        float u = th * rn * scale * val[r];
        float un = pn * scale;
        u16 h,l; bsplit(u,h,l);
        Kch[(size_t)s*D_TOT + nBase + lane] = h;
        Kcl[(size_t)s*D_TOT + nBase + lane] = l;
        if (lane == 0) vh2a[s] = un*un;
      }
    }
  } else {
    if (blockIdx.x < 7) {
#pragma unroll
      for (int r = 0; r < 8; ++r) {
        const int s = mBase + erow + r;
        Qch[(size_t)s*D_TOT + nBase + lane] = bf16rne(val[r]);
        float p = wave_sum64(val[r]*val[r]);
        if (lane == 0) qnpart[s*8 + blockIdx.x] = p;
      }
    } else {
#pragma unroll
      for (int r = 0; r < 8; ++r) {
        const int s = mBase + erow + r;
        float n2 = wave_sum64(val[r]*val[r]);
        float nn = sqrtf(n2);
        float n  = fmaxf(nn, 1e-5f);
        float e2n = __expf(2.f*n);
        float th  = 1.f - 2.f*frcp(e2n + 1.f);
        float rn  = frcp(n);
        float pn  = th * nn * rn;
        float scale = fminf(0.999f * frcp(fmaxf(pn, 1e-5f)), 1.f);
        float u = th * rn * scale * val[r];
        float un = pn * scale;
        Qch[(size_t)s*D_TOT + nBase + lane] = bf16rne(u);
        if (lane == 0) uh2a[s] = un*un;
      }
    }
  }
}

// ================= score: 32x64 tile, grid (16,32)=512, dbuf, 2 blocks/CU resident =================
// 8 waves = 2(kg) x 4(wc, 16-col groups). Per kg: 224 euclid (7 steps) + 32 hyper (step 7).
__global__ __launch_bounds__(512,4) void score_mfma(
    const u16* __restrict__ Qch,
    const u16* __restrict__ Kch, const u16* __restrict__ Kcl,
    const float* __restrict__ qnpart, const float* __restrict__ knpart,
    const float* __restrict__ uh2a, const float* __restrict__ vh2a,
    const float* __restrict__ alpha_u,
    u16* __restrict__ Eh, float* __restrict__ rowpart)
{
  // stage: 2 bufs x [2 kg][A 32x40 | Bh 64x40 | Bl 64x40] u16 = 51200 B
  // fbuf overlay: E [2][32][68] + H [2][32][68] = 8704 f = 34816 B
  __shared__ __align__(16) char shm_[51200];
  __shared__ float rowscal[192];   // qn[0..31] kn[32..95] u2[96..127] v2[128..191]
  u16* stg = (u16*)shm_;
  float* fbuf = (float*)shm_;
  const int t = threadIdx.x, lane = t & 63, wave = t >> 6;
  const int mBase = blockIdx.y << 5, nBase = blockIdx.x << 6;
  if (t < 32) {
    float s_ = 0.f;
#pragma unroll
    for (int c = 0; c < 7; ++c) s_ += qnpart[(mBase+t)*8 + c];
    rowscal[t] = s_;
  } else if (t < 96) {
    float s_ = 0.f;
#pragma unroll
    for (int c = 0; c < 7; ++c) s_ += knpart[(nBase+t-32)*8 + c];
    rowscal[t] = s_;
  } else if (t < 128) rowscal[t] = uh2a[mBase + t - 96];
  else if (t < 192)   rowscal[t] = vh2a[nBase + t - 128];

  const int kg = t >> 8, sub = t & 255;
  const int wkg = wave >> 2, wc = wave & 3;
  const int arow = sub >> 3, acol4 = (sub & 7) << 2;
  const int brow = sub >> 2, bcol8 = (sub & 3) << 3;

  const u16* Agh = Qch + (size_t)(mBase + arow)*D_TOT + acol4;
  const u16* Bgh = Kch + (size_t)(nBase + brow)*D_TOT + bcol8;
  const u16* Bgl = Kcl + (size_t)(nBase + brow)*D_TOT + bcol8;

  const int sA  = kg*6400 + arow*40 + acol4;
  const int sBh = kg*6400 + 1280 + brow*40 + bcol8;
  const int sBl = kg*6400 + 3840 + brow*40 + bcol8;
  const int fa  = wkg*6400 + (lane&15)*40 + ((lane>>4)<<3);
  const int fbh = wkg*6400 + 1280 + (wc*16 + (lane&15))*40 + ((lane>>4)<<3);
  const int fbl = wkg*6400 + 3840 + (wc*16 + (lane&15))*40 + ((lane>>4)<<3);

  int kb = kg * 224;
  uint2 rA  = *(const uint2*)(Agh + kb);
  uint4 rBh = *(const uint4*)(Bgh + kb), rBl = *(const uint4*)(Bgl + kb);
  *(uint2*)&stg[sA ] = rA;
  *(uint4*)&stg[sBh] = rBh;
  *(uint4*)&stg[sBl] = rBl;
  kb = kg * 224 + 32;
  rA  = *(const uint2*)(Agh + kb);
  rBh = *(const uint4*)(Bgh + kb); rBl = *(const uint4*)(Bgl + kb);

  f32x4 zero = {0.f,0.f,0.f,0.f};
  f32x4 accE[2] = {zero, zero};
  f32x4 accH[2] = {zero, zero};
#pragma unroll
  for (int r = 0; r < 8; ++r) {
    __syncthreads();
    const u16* bufr = stg + (r & 1) * 12800;
    bf16x8 fAh[2], fBhv, fBlv;
    fAh[0] = *(const bf16x8*)&bufr[fa];
    fAh[1] = *(const bf16x8*)&bufr[fa + 640];
    fBhv   = *(const bf16x8*)&bufr[fbh];
    fBlv   = *(const bf16x8*)&bufr[fbl];
    if (r + 1 < 8) {
      u16* bufw = stg + ((r + 1) & 1) * 12800;
      *(uint2*)&bufw[sA ] = rA;
      *(uint4*)&bufw[sBh] = rBh;
      *(uint4*)&bufw[sBl] = rBl;
      if (r + 2 < 8) {
        const int o = (r + 2 < 7) ? (kg*224 + (r+2)*32) : (448 + kg*32);
        rA  = *(const uint2*)(Agh + o);
        rBh = *(const uint4*)(Bgh + o); rBl = *(const uint4*)(Bgl + o);
      }
    }
    if (r < 7) {
#pragma unroll
      for (int i = 0; i < 2; ++i) {
        accE[i] = __builtin_amdgcn_mfma_f32_16x16x32_bf16(fAh[i], fBhv, accE[i], 0,0,0);
        accE[i] = __builtin_amdgcn_mfma_f32_16x16x32_bf16(fAh[i], fBlv, accE[i], 0,0,0);
      }
    } else {
#pragma unroll
      for (int i = 0; i < 2; ++i) {
        accH[i] = __builtin_amdgcn_mfma_f32_16x16x32_bf16(fAh[i], fBhv, accH[i], 0,0,0);
        accH[i] = __builtin_amdgcn_mfma_f32_16x16x32_bf16(fAh[i], fBlv, accH[i], 0,0,0);
      }
    }
  }

  // --- cross-kg reduction ---
  __syncthreads();
  {
    const int r0 = (lane>>4)<<2;
    const int c0 = wc*16 + (lane&15);
#pragma unroll
    for (int i = 0; i < 2; ++i)
#pragma unroll
      for (int g = 0; g < 4; ++g) {
        fbuf[       wkg*2176 + (i*16 + r0 + g)*68 + c0] = accE[i][g];
        fbuf[4352 + wkg*2176 + (i*16 + r0 + g)*68 + c0] = accH[i][g];
      }
  }
  __syncthreads();

  // --- transcendental epilogue: 8 waves x 4 rows, 64 cols/lane ---
  const float alpha = __logf(1.f + __expf(alpha_u[0]));
  const float inv_s = 0.04419417382415922f;
  const float knl = rowscal[32 + lane], v2 = rowscal[128 + lane];
#pragma unroll
  for (int rr = 0; rr < 4; ++rr) {
    const int row = (wave << 2) + rr;
    const int s = mBase + row;
    float eE = fbuf[row*68 + lane] + fbuf[2176 + row*68 + lane];
    float dH = fbuf[4352 + row*68 + lane] + fbuf[6528 + row*68 + lane];
    const float qns = rowscal[row], u2 = rowscal[96 + row];
    float de   = qns + knl - 2.f * eE;
    float Ac   = 1.f - 2.f*dH + v2;
    float Bc   = 1.f - u2;
    float num2 = Ac*Ac*u2 + Bc*Bc*v2 - 2.f*Ac*Bc*dH;
    float den  = fmaxf(1.f - 2.f*dH + u2*v2, 1e-5f);
    float frac = sqrtf(fmaxf(num2, 0.f)) * frcp(den);
    float nrm  = fminf(frac, 0.999f);
    float dh_  = __logf((1.f + nrm) * frcp(1.f - nrm));
    float dist = de + alpha * dh_ * dh_;
    float lg   = fminf(fmaxf(-dist * inv_s, -50.f), 0.f);
    float e    = __expf(lg);
    Eh[(size_t)s*S_LEN + nBase + lane] = bf16rne(e);
    float rs = wave_sum64(e);
    if (lane == 0) rowpart[s*16 + blockIdx.x] = rs;
  }
}

// ================= attn @ V: 32x32 tile, grid (16,32)=512, dbuf, 2 blocks/CU =================
// 8 waves = 4(kg, K=256 each) x 2(wc, 16-col groups). 8 steps of BK=32. E hi x (Vh+Vl).
__global__ __launch_bounds__(512,4) void av_mfma(
    const u16* __restrict__ Eh,
    const u16* __restrict__ vTh, const u16* __restrict__ vTl,
    const float* __restrict__ rowpart,
    u16* __restrict__ out1h)
{
  // stage: 2 bufs x [4 kg][A 32x40 | Bh 32x40 | Bl 32x40] u16 = 61440 B
  // fbuf overlay: [4 kg][32][36] = 4608 f = 18432 B
  __shared__ __align__(16) char shm_[61440];
  __shared__ float rinvl[32];
  u16* stg = (u16*)shm_;
  float* fbuf = (float*)shm_;
  const int t = threadIdx.x, lane = t & 63, wave = t >> 6;
  const int mBase = blockIdx.y << 5, nBase = blockIdx.x << 5;
  if (t < 32) {
    float s_ = 0.f;
#pragma unroll
    for (int c = 0; c < 16; ++c) s_ += rowpart[(mBase+t)*16 + c];
    rinvl[t] = 1.f / s_;
  }
  const int kg = t >> 7, sub = t & 127;
  const int wc = wave & 1;
  const int ar = sub >> 2, ac8 = (sub & 3) << 3;

  const u16* Ag = Eh  + (size_t)(mBase + ar)*S_LEN + kg*256 + ac8;
  const u16* Bh = vTh + (size_t)(nBase + ar)*S_LEN + kg*256 + ac8;
  const u16* Bl = vTl + (size_t)(nBase + ar)*S_LEN + kg*256 + ac8;

  const int sA  = kg*3840 + ar*40 + ac8;
  const int sBh = kg*3840 + 1280 + ar*40 + ac8;
  const int sBl = kg*3840 + 2560 + ar*40 + ac8;
  const int fa  = kg*3840 + (lane&15)*40 + ((lane>>4)<<3);
  const int fbh = kg*3840 + 1280 + (wc*16 + (lane&15))*40 + ((lane>>4)<<3);
  const int fbl = kg*3840 + 2560 + (wc*16 + (lane&15))*40 + ((lane>>4)<<3);

  uint4 rA  = *(const uint4*)Ag;
  uint4 rBh = *(const uint4*)Bh, rBl = *(const uint4*)Bl;
  *(uint4*)&stg[sA ] = rA;
  *(uint4*)&stg[sBh] = rBh;
  *(uint4*)&stg[sBl] = rBl;
  rA  = *(const uint4*)(Ag + 32);
  rBh = *(const uint4*)(Bh + 32); rBl = *(const uint4*)(Bl + 32);

  f32x4 zero = {0.f,0.f,0.f,0.f};
  f32x4 acc[2] = {zero, zero};
#pragma unroll
  for (int r = 0; r < 8; ++r) {
    __syncthreads();
    const u16* bufr = stg + (r & 1) * 15360;
    bf16x8 fAh[2], fBhv, fBlv;
    fAh[0] = *(const bf16x8*)&bufr[fa];
    fAh[1] = *(const bf16x8*)&bufr[fa + 640];
    fBhv   = *(const bf16x8*)&bufr[fbh];
    fBlv   = *(const bf16x8*)&bufr[fbl];
    if (r + 1 < 8) {
      u16* bufw = stg + ((r + 1) & 1) * 15360;
      *(uint4*)&bufw[sA ] = rA;
      *(uint4*)&bufw[sBh] = rBh;
      *(uint4*)&bufw[sBl] = rBl;
      if (r + 2 < 8) {
        const int o = (r + 2) * 32;
        rA  = *(const uint4*)(Ag + o);
        rBh = *(const uint4*)(Bh + o); rBl = *(const uint4*)(Bl + o);
      }
    }
#pragma unroll
    for (int i = 0; i < 2; ++i) {
      acc[i] = __builtin_amdgcn_mfma_f32_16x16x32_bf16(fAh[i], fBhv, acc[i], 0,0,0);
      acc[i] = __builtin_amdgcn_mfma_f32_16x16x32_bf16(fAh[i], fBlv, acc[i], 0,0,0);
    }
  }

  // --- cross-kg reduction: [4 kg][32][36] ---
  __syncthreads();
  {
    const int r0 = (lane>>4)<<2;
    const int c0 = wc*16 + (lane&15);
#pragma unroll
    for (int i = 0; i < 2; ++i)
#pragma unroll
      for (int g = 0; g < 4; ++g)
        fbuf[kg*1152 + (i*16 + r0 + g)*36 + c0] = acc[i][g];
  }
  __syncthreads();
  const int col = lane & 31, half = lane >> 5;
#pragma unroll
  for (int rr = 0; rr < 2; ++rr) {
    const int row = (wave << 2) + (half << 1) + rr;
    float e = 0.f;
#pragma unroll
    for (int g = 0; g < 4; ++g) e += fbuf[g*1152 + row*36 + col];
    float v_ = e * rinvl[row];
    const int s = mBase + row;
    out1h[(size_t)s*D_TOT + nBase + col] = bf16rne(v_);
  }
}

// ================= final (round-8 verbatim): out = out1h @ wo.T + bo =================
__global__ __launch_bounds__(512,4) void final_mfma(
    const u16* __restrict__ out1h,
    const float* __restrict__ wo, const float* __restrict__ bo,
    float* __restrict__ out)
{
  __shared__ __align__(16) u16 stg[25600];
  float* fbuf = (float*)stg;
  const int t = threadIdx.x, lane = t & 63, wave = t >> 6;
  const int mBase = blockIdx.y << 5, nBase = blockIdx.x << 6;
  const int kg = t >> 7, sub = t & 127;
  const int arow = sub >> 2, acol = (sub & 3) << 3;
  const int brow0 = sub >> 2, bcol0 = (sub & 3) << 3;
  const int brow1 = (sub + 128) >> 2, bcol1 = ((sub + 128) & 3) << 3;
  const int kgw = wave >> 1, wc = wave & 1;

  const u16* Ag = out1h + (size_t)(mBase+arow)*D_TOT + acol + kg*128;
  const float* B0 = wo + (size_t)(nBase+brow0)*D_TOT + bcol0 + kg*128;
  const float* B1 = wo + (size_t)(nBase+brow1)*D_TOT + bcol1 + kg*128;

  const int sA  = kg*6400 + arow*40 + acol;
  const int sB0 = kg*6400 + 1280 + brow0*40 + bcol0;
  const int sB1 = kg*6400 + 1280 + brow1*40 + bcol1;
  const int fa  = kgw*6400 + (lane&15)*40 + ((lane>>4)<<3);
  const int fbh = kgw*6400 + 1280 + (wc*32 + (lane&15))*40 + ((lane>>4)<<3);

  uint4 rA = *(const uint4*)Ag;
  float4 b00 = *(const float4*)B0, b01 = *(const float4*)(B0 + 4);
  float4 b10 = *(const float4*)B1, b11 = *(const float4*)(B1 + 4);

  f32x4 zero = {0.f,0.f,0.f,0.f};
  f32x4 acc[2][2] = {{zero,zero},{zero,zero}};
#pragma unroll
  for (int r = 0; r < 4; ++r) {
    __syncthreads();
    uint4 bh0,bl0,bh1,bl1;
    bsplit8(b00,b01,bh0,bl0); bsplit8(b10,b11,bh1,bl1);
    *(uint4*)&stg[sA        ] = rA;
    *(uint4*)&stg[sB0       ] = bh0; *(uint4*)&stg[sB0 + 2560] = bl0;
    *(uint4*)&stg[sB1       ] = bh1; *(uint4*)&stg[sB1 + 2560] = bl1;
    if (r + 1 < 4) {
      const int o = (r + 1) * 32;
      rA = *(const uint4*)(Ag + o);
      b00 = *(const float4*)(B0 + o); b01 = *(const float4*)(B0 + o + 4);
      b10 = *(const float4*)(B1 + o); b11 = *(const float4*)(B1 + o + 4);
    }
    __syncthreads();
    bf16x8 fAh[2], fBh[2], fBl[2];
#pragma unroll
    for (int i = 0; i < 2; ++i) {
      fAh[i] = *(const bf16x8*)&stg[fa         + i*640];
      fBh[i] = *(const bf16x8*)&stg[fbh        + i*640];
      fBl[i] = *(const bf16x8*)&stg[fbh + 2560 + i*640];
    }
    MFMA2(acc);
  }

  __syncthreads();
  {
    const int r0 = (lane>>4)<<2;
    const int c0 = wc*32 + (lane&15);
#pragma unroll
    for (int i = 0; i < 2; ++i)
#pragma unroll
      for (int j = 0; j < 2; ++j)
#pragma unroll
        for (int g = 0; g < 4; ++g)
          fbuf[kgw*2176 + (r0 + i*16 + g)*68 + c0 + j*16] = acc[i][j][g];
  }
  __syncthreads();
  const int erow = wave << 2;
  const float b = bo[nBase + lane];
#pragma unroll
  for (int r = 0; r < 4; ++r) {
    const int row = erow + r;
    float e = fbuf[row*68 + lane] + fbuf[2176 + row*68 + lane]
            + fbuf[4352 + row*68 + lane] + fbuf[6528 + row*68 + lane];
    out[(size_t)(mBase+row)*D_TOT + nBase + lane] = e + b;
  }
}

extern "C" void kernel_launch(void* const* d_in, const int* in_sizes, int n_in,
                              void* d_out, int out_size, void* d_ws, size_t ws_size,
                              hipStream_t stream)
{
  const float* x   = (const float*)d_in[0];
  const float* wq  = (const float*)d_in[1];
  const float* bq  = (const float*)d_in[2];
  const float* wk  = (const float*)d_in[3];
  const float* bk  = (const float*)d_in[4];
  const float* wv  = (const float*)d_in[5];
  const float* bv  = (const float*)d_in[6];
  const float* wo  = (const float*)d_in[7];
  const float* bo  = (const float*)d_in[8];
  const float* alpha_u = (const float*)d_in[9];
  float* out = (float*)d_out;

  u16* U = (u16*)d_ws;
  u16* Qch   = U + 0;
  u16* Kch   = U + 524288;
  u16* Kcl   = U + 1048576;
  u16* vTh   = U + 1572864;
  u16* vTl   = U + 2097152;
  u16* Eh    = U + 2621440;
  u16* out1h = U + 3670016;
  float* F = (float*)(U + 4194304);
  float* qnpart  = F;
  float* knpart  = F + 8192;
  float* uh2a    = F + 16384;
  float* vh2a    = F + 17408;
  float* rowpart = F + 18432;

  qkv_mfma<<<dim3(8,16,3), 512, 0, stream>>>(x, wq,bq, wk,bk, wv,bv,
      Qch, Kch, Kcl, vTh, vTl, qnpart, knpart, uh2a, vh2a);
  score_mfma<<<dim3(16,32), 512, 0, stream>>>(Qch, Kch, Kcl,
      qnpart, knpart, uh2a, vh2a, alpha_u, Eh, rowpart);
  av_mfma<<<dim3(16,32), 512, 0, stream>>>(Eh, vTh, vTl, rowpart, out1h);
  final_mfma<<<dim3(8,32), 512, 0, stream>>>(out1h, wo, bo, out);
}

// Round 14
// 38.152 us; speedup vs baseline: 1.3409x; 1.1510x over previous
//
#include <hip/hip_runtime.h>

#define S_LEN 1024
#define D_TOT 512
#define D_E   448

typedef short bf16x8 __attribute__((ext_vector_type(8)));
typedef float f32x4  __attribute__((ext_vector_type(4)));
typedef unsigned short u16;

__device__ __forceinline__ float frcp(float x) {
  float r; asm("v_rcp_f32 %0, %1" : "=v"(r) : "v"(x)); return r;
}

__device__ __forceinline__ float wave_sum64(float v) {
#pragma unroll
  for (int o = 32; o > 0; o >>= 1) v += __shfl_xor(v, o);
  return v;
}

__device__ __forceinline__ u16 bf16rne(float f) {
  unsigned u = __builtin_bit_cast(unsigned, f);
  return (u16)((u + 0x7fffu + ((u >> 16) & 1u)) >> 16);
}

__device__ __forceinline__ void bsplit(float f, u16 &h, u16 &l) {
  unsigned u  = __builtin_bit_cast(unsigned, f);
  unsigned ur = u + 0x7fffu + ((u >> 16) & 1u);
  h = (u16)(ur >> 16);
  float fh = __builtin_bit_cast(float, ur & 0xffff0000u);
  float r  = f - fh;
  l = bf16rne(r);
}

__device__ __forceinline__ void bsplit8(float4 a, float4 b, uint4 &h, uint4 &l) {
  u16 h0,h1,h2,h3,h4,h5,h6,h7, l0,l1,l2,l3,l4,l5,l6,l7;
  bsplit(a.x,h0,l0); bsplit(a.y,h1,l1); bsplit(a.z,h2,l2); bsplit(a.w,h3,l3);
  bsplit(b.x,h4,l4); bsplit(b.y,h5,l5); bsplit(b.z,h6,l6); bsplit(b.w,h7,l7);
  h.x = (unsigned)h0 | ((unsigned)h1<<16); h.y = (unsigned)h2 | ((unsigned)h3<<16);
  h.z = (unsigned)h4 | ((unsigned)h5<<16); h.w = (unsigned)h6 | ((unsigned)h7<<16);
  l.x = (unsigned)l0 | ((unsigned)l1<<16); l.y = (unsigned)l2 | ((unsigned)l3<<16);
  l.z = (unsigned)l4 | ((unsigned)l5<<16); l.w = (unsigned)l6 | ((unsigned)l7<<16);
}

__device__ __forceinline__ uint4 rne8(float4 a, float4 b) {
  uint4 h;
  h.x = (unsigned)bf16rne(a.x) | ((unsigned)bf16rne(a.y)<<16);
  h.y = (unsigned)bf16rne(a.z) | ((unsigned)bf16rne(a.w)<<16);
  h.z = (unsigned)bf16rne(b.x) | ((unsigned)bf16rne(b.y)<<16);
  h.w = (unsigned)bf16rne(b.z) | ((unsigned)bf16rne(b.w)<<16);
  return h;
}

#define MFMA2(ACC)                                                                              \
  _Pragma("unroll") for (int i_ = 0; i_ < 2; ++i_)                                              \
  _Pragma("unroll") for (int j_ = 0; j_ < 2; ++j_) {                                            \
    ACC[i_][j_] = __builtin_amdgcn_mfma_f32_16x16x32_bf16(fAh[i_], fBh[j_], ACC[i_][j_],0,0,0); \
    ACC[i_][j_] = __builtin_amdgcn_mfma_f32_16x16x32_bf16(fAh[i_], fBl[j_], ACC[i_][j_],0,0,0); \
  }

#define MFMA1(ACC)                                                                              \
  _Pragma("unroll") for (int i_ = 0; i_ < 2; ++i_)                                              \
  _Pragma("unroll") for (int j_ = 0; j_ < 2; ++j_)                                              \
    ACC[i_][j_] = __builtin_amdgcn_mfma_f32_16x16x32_bf16(fAh[i_], fBh[j_], ACC[i_][j_],0,0,0);

// ================= QKV: q/k/v = x @ W.T + b (x hi, W hi/lo; K,V stored hi-only) =================
__global__ __launch_bounds__(512,4) void qkv_mfma(
    const float* __restrict__ x,
    const float* __restrict__ wq, const float* __restrict__ bq,
    const float* __restrict__ wk, const float* __restrict__ bk,
    const float* __restrict__ wv, const float* __restrict__ bv,
    u16* __restrict__ Qch, u16* __restrict__ Kch, u16* __restrict__ vTh,
    float* __restrict__ qnpart, float* __restrict__ knpart,
    float* __restrict__ uh2a, float* __restrict__ vh2a)
{
  __shared__ __align__(16) u16 stage[2][15360];
  float* fbuf = (float*)stage;
  const int z = blockIdx.z;
  const float* W; const float* bias;
  if (z == 0)      { W = wq; bias = bq; }
  else if (z == 1) { W = wk; bias = bk; }
  else             { W = wv; bias = bv; }
  const int mBase = blockIdx.y << 6, nBase = blockIdx.x << 6;
  const int t = threadIdx.x, lane = t & 63, wave = t >> 6;
  const int kg = t >> 8, sub = t & 255;
  const int srow = sub >> 2, scol = (sub & 3) << 3;
  const int kgw = wave >> 2, wr = (wave >> 1) & 1, wc = wave & 1;

  const float* Ag = x + (size_t)(mBase + srow) * D_TOT + scol + kg * 256;
  const float* Bg = W + (size_t)(nBase + srow) * D_TOT + scol + kg * 256;

  const int sb = kg * 7680 + srow * 40 + scol;
  const int fa = kgw * 7680 + (wr * 32 + (lane & 15)) * 40 + ((lane >> 4) << 3);
  const int fb = kgw * 7680 + 2560 + (wc * 32 + (lane & 15)) * 40 + ((lane >> 4) << 3);

  float4 a0 = *(const float4*)Ag, a1 = *(const float4*)(Ag + 4);
  float4 b0 = *(const float4*)Bg, b1 = *(const float4*)(Bg + 4);
  {
    uint4 hB,lB; bsplit8(b0,b1,hB,lB);
    *(uint4*)&stage[0][sb       ] = rne8(a0,a1);
    *(uint4*)&stage[0][sb + 2560] = hB;
    *(uint4*)&stage[0][sb + 5120] = lB;
  }
  a0 = *(const float4*)(Ag + 32); a1 = *(const float4*)(Ag + 36);
  b0 = *(const float4*)(Bg + 32); b1 = *(const float4*)(Bg + 36);

  f32x4 zero = {0.f,0.f,0.f,0.f};
  f32x4 acc[2][2] = {{zero,zero},{zero,zero}};
#pragma unroll
  for (int r = 0; r < 8; ++r) {
    __syncthreads();
    const u16* bufr = stage[r & 1];
    bf16x8 fAh[2], fBh[2], fBl[2];
#pragma unroll
    for (int i = 0; i < 2; ++i) {
      fAh[i] = *(const bf16x8*)&bufr[fa        + i*640];
      fBh[i] = *(const bf16x8*)&bufr[fb        + i*640];
      fBl[i] = *(const bf16x8*)&bufr[fb + 2560 + i*640];
    }
    if (r + 1 < 8) {
      u16* bufw = stage[(r + 1) & 1];
      uint4 hB,lB; bsplit8(b0,b1,hB,lB);
      *(uint4*)&bufw[sb       ] = rne8(a0,a1);
      *(uint4*)&bufw[sb + 2560] = hB;
      *(uint4*)&bufw[sb + 5120] = lB;
      if (r + 2 < 8) {
        const int o = (r + 2) * 32;
        a0 = *(const float4*)(Ag + o); a1 = *(const float4*)(Ag + o + 4);
        b0 = *(const float4*)(Bg + o); b1 = *(const float4*)(Bg + o + 4);
      }
    }
    MFMA2(acc);
  }

  __syncthreads();
  {
    const int r0 = wr*32 + ((lane>>4)<<2);
    const int c0 = wc*32 + (lane&15);
#pragma unroll
    for (int i = 0; i < 2; ++i)
#pragma unroll
      for (int j = 0; j < 2; ++j)
#pragma unroll
        for (int g = 0; g < 4; ++g)
          fbuf[kgw*4352 + (r0 + i*16 + g)*68 + c0 + j*16] = acc[i][j][g];
  }
  __syncthreads();
  const int erow = wave << 3;
  float val[8];
  {
    const float b = bias[nBase + lane];
#pragma unroll
    for (int r = 0; r < 8; ++r)
      val[r] = fbuf[(erow+r)*68 + lane] + fbuf[4352 + (erow+r)*68 + lane] + b;
  }

  if (z == 2) {
    u16 hh[8];
#pragma unroll
    for (int r = 0; r < 8; ++r) hh[r] = bf16rne(val[r]);
    const size_t off = (size_t)(nBase + lane) * S_LEN + mBase + erow;
    ushort4 p0{hh[0],hh[1],hh[2],hh[3]}, p1{hh[4],hh[5],hh[6],hh[7]};
    *(ushort4*)(vTh + off) = p0; *(ushort4*)(vTh + off + 4) = p1;
  } else {
    u16* Ch = z ? Kch : Qch;
    float* np_ = z ? knpart : qnpart;
    float* u2a = z ? vh2a  : uh2a;
    if (blockIdx.x < 7) {
#pragma unroll
      for (int r = 0; r < 8; ++r) {
        const int s = mBase + erow + r;
        Ch[(size_t)s*D_TOT + nBase + lane] = bf16rne(val[r]);
        float p = wave_sum64(val[r]*val[r]);
        if (lane == 0) np_[s*8 + blockIdx.x] = p;
      }
    } else {
#pragma unroll
      for (int r = 0; r < 8; ++r) {
        const int s = mBase + erow + r;
        float n2 = wave_sum64(val[r]*val[r]);
        float nn = sqrtf(n2);
        float n  = fmaxf(nn, 1e-5f);
        float e2n = __expf(2.f*n);
        float th  = 1.f - 2.f*frcp(e2n + 1.f);
        float rn  = frcp(n);
        float pn  = th * nn * rn;
        float scale = fminf(0.999f * frcp(fmaxf(pn, 1e-5f)), 1.f);
        float u = th * rn * scale * val[r];
        float un = pn * scale;
        Ch[(size_t)s*D_TOT + nBase + lane] = bf16rne(u);
        if (lane == 0) u2a[s] = un*un;
      }
    }
  }
}

// ================= score: Q hi x K hi (MFMA1), dbuf, 64x64 tile =================
__global__ __launch_bounds__(512,4) void score_mfma(
    const u16* __restrict__ Qch, const u16* __restrict__ Kch,
    const float* __restrict__ qnpart, const float* __restrict__ knpart,
    const float* __restrict__ uh2a, const float* __restrict__ vh2a,
    const float* __restrict__ alpha_u,
    u16* __restrict__ Eh, float* __restrict__ rowpart)
{
  // stage: 2 bufs x [2 kg][A 64x40 | B 64x40] u16 = 40960 B; fbuf overlay 69632 B
  __shared__ __align__(16) char shm_[69632];
  __shared__ float rowscal[256];
  u16* stg = (u16*)shm_;
  float* fbuf = (float*)shm_;
  const int t = threadIdx.x, lane = t & 63, wave = t >> 6;
  const int mBase = blockIdx.y << 6, nBase = blockIdx.x << 6;
  if (t < 64) {
    float s_ = 0.f;
#pragma unroll
    for (int c = 0; c < 7; ++c) s_ += qnpart[(mBase+t)*8 + c];
    rowscal[t] = s_;
  } else if (t < 128) {
    float s_ = 0.f;
#pragma unroll
    for (int c = 0; c < 7; ++c) s_ += knpart[(nBase+t-64)*8 + c];
    rowscal[t] = s_;
  } else if (t < 192) rowscal[t] = uh2a[mBase + t - 128];
  else if (t < 256)   rowscal[t] = vh2a[nBase + t - 192];

  const int kg = t >> 8, sub = t & 255;
  const int srow = sub >> 2, scol = (sub & 3) << 3;
  const int kgw = wave >> 2, wr = (wave >> 1) & 1, wc = wave & 1;
  const u16* Agh = Qch + (size_t)(mBase+srow)*D_TOT + scol;
  const u16* Bgh = Kch + (size_t)(nBase+srow)*D_TOT + scol;

  const int sb  = kg * 5120 + srow * 40 + scol;
  const int fa  = kgw * 5120 + (wr * 32 + (lane & 15)) * 40 + ((lane >> 4) << 3);
  const int fbh = kgw * 5120 + 2560 + (wc * 32 + (lane & 15)) * 40 + ((lane >> 4) << 3);

  int kb = kg * 224;
  uint4 rAh = *(const uint4*)(Agh + kb);
  uint4 rBh = *(const uint4*)(Bgh + kb);
  *(uint4*)&stg[sb       ] = rAh;
  *(uint4*)&stg[sb + 2560] = rBh;
  kb = kg * 224 + 32;
  rAh = *(const uint4*)(Agh + kb);
  rBh = *(const uint4*)(Bgh + kb);

  f32x4 zero = {0.f,0.f,0.f,0.f};
  f32x4 accE[2][2] = {{zero,zero},{zero,zero}};
  f32x4 accH[2][2] = {{zero,zero},{zero,zero}};
#pragma unroll
  for (int r = 0; r < 8; ++r) {
    __syncthreads();
    const u16* bufr = stg + (r & 1) * 10240;
    bf16x8 fAh[2], fBh[2];
#pragma unroll
    for (int i = 0; i < 2; ++i) {
      fAh[i] = *(const bf16x8*)&bufr[fa  + i*640];
      fBh[i] = *(const bf16x8*)&bufr[fbh + i*640];
    }
    if (r + 1 < 8) {
      u16* bufw = stg + ((r + 1) & 1) * 10240;
      *(uint4*)&bufw[sb       ] = rAh;
      *(uint4*)&bufw[sb + 2560] = rBh;
      if (r + 2 < 8) {
        const int o = (r + 2 < 7) ? (kg*224 + (r+2)*32) : (448 + kg*32);
        rAh = *(const uint4*)(Agh + o);
        rBh = *(const uint4*)(Bgh + o);
      }
    }
    if (r < 7) { MFMA1(accE) } else { MFMA1(accH) }
  }

  __syncthreads();
  {
    const int r0 = wr*32 + ((lane>>4)<<2);
    const int c0 = wc*32 + (lane&15);
#pragma unroll
    for (int i = 0; i < 2; ++i)
#pragma unroll
      for (int j = 0; j < 2; ++j)
#pragma unroll
        for (int g = 0; g < 4; ++g) {
          fbuf[       kgw*4352 + (r0 + i*16 + g)*68 + c0 + j*16] = accE[i][j][g];
          fbuf[8704 + kgw*4352 + (r0 + i*16 + g)*68 + c0 + j*16] = accH[i][j][g];
        }
  }
  __syncthreads();
  const int erow = wave << 3;
  float eE[8], eH[8];
#pragma unroll
  for (int r = 0; r < 8; ++r) {
    eE[r] = fbuf[(erow+r)*68 + lane] + fbuf[4352 + (erow+r)*68 + lane];
    eH[r] = fbuf[8704 + (erow+r)*68 + lane] + fbuf[8704 + 4352 + (erow+r)*68 + lane];
  }

  const float alpha = __logf(1.f + __expf(alpha_u[0]));
  const float inv_s = 0.04419417382415922f;
  const float knl = rowscal[64 + lane], v2 = rowscal[192 + lane];
#pragma unroll
  for (int r = 0; r < 8; ++r) {
    const int s = mBase + erow + r;
    const float qns = rowscal[erow + r], u2 = rowscal[128 + erow + r];
    float de   = qns + knl - 2.f * eE[r];
    float dH   = eH[r];
    float Ac   = 1.f - 2.f*dH + v2;
    float Bc   = 1.f - u2;
    float num2 = Ac*Ac*u2 + Bc*Bc*v2 - 2.f*Ac*Bc*dH;
    float den  = fmaxf(1.f - 2.f*dH + u2*v2, 1e-5f);
    float frac = sqrtf(fmaxf(num2, 0.f)) * frcp(den);
    float nrm  = fminf(frac, 0.999f);
    float dh_  = __logf((1.f + nrm) * frcp(1.f - nrm));
    float dist = de + alpha * dh_ * dh_;
    float lg   = fminf(fmaxf(-dist * inv_s, -50.f), 0.f);
    float e    = __expf(lg);
    Eh[(size_t)s*S_LEN + nBase + lane] = bf16rne(e);
    float rs = wave_sum64(e);
    if (lane == 0) rowpart[s*16 + blockIdx.x] = rs;
  }
}

// ================= av: out1 = diag(rinv) * (E @ vT^T), E hi x V hi (MFMA1), dbuf =================
// 32x64 tile, 8 waves = 4(kg) x 2(wc), K=1024, 8 steps of BK=32.
__global__ __launch_bounds__(512,4) void av_mfma(
    const u16* __restrict__ Eh, const u16* __restrict__ vTh,
    const float* __restrict__ rowpart,
    u16* __restrict__ out1h)
{
  __shared__ __align__(16) u16 stage[2][15360];  // per buf: [4 kg][A 1280 | B 2560]
  __shared__ float rinvl[32];
  float* fbuf = (float*)stage;                   // [4 kg][32][68]
  const int t = threadIdx.x, lane = t & 63, wave = t >> 6;
  const int mBase = blockIdx.y << 5, nBase = blockIdx.x << 6;
  if (t < 32) {
    float s_ = 0.f;
#pragma unroll
    for (int c = 0; c < 16; ++c) s_ += rowpart[(mBase+t)*16 + c];
    rinvl[t] = 1.f / s_;
  }
  const int kg = t >> 7, sub = t & 127;
  const int arow = sub >> 2, acol = (sub & 3) << 3;
  const int brow0 = sub >> 2, brow1 = 32 + (sub >> 2), bcol = (sub & 3) << 3;
  const int kgw = wave >> 1, wc = wave & 1;

  const u16* Ag = Eh  + (size_t)(mBase+arow)*S_LEN + kg*256 + acol;
  const u16* B0 = vTh + (size_t)(nBase+brow0)*S_LEN + kg*256 + bcol;
  const u16* B1 = vTh + (size_t)(nBase+brow1)*S_LEN + kg*256 + bcol;

  const int sA  = kg*3840 + arow*40 + acol;
  const int sB0 = kg*3840 + 1280 + brow0*40 + bcol;
  const int sB1 = kg*3840 + 1280 + brow1*40 + bcol;
  const int fa  = kgw*3840 + (lane&15)*40 + ((lane>>4)<<3);
  const int fb  = kgw*3840 + 1280 + (wc*32 + (lane&15))*40 + ((lane>>4)<<3);

  uint4 rA = *(const uint4*)Ag;
  uint4 rb0 = *(const uint4*)B0, rb1 = *(const uint4*)B1;
  *(uint4*)&stage[0][sA ] = rA;
  *(uint4*)&stage[0][sB0] = rb0; *(uint4*)&stage[0][sB1] = rb1;
  rA = *(const uint4*)(Ag + 32);
  rb0 = *(const uint4*)(B0 + 32); rb1 = *(const uint4*)(B1 + 32);

  f32x4 zero = {0.f,0.f,0.f,0.f};
  f32x4 acc[2][2] = {{zero,zero},{zero,zero}};
#pragma unroll
  for (int r = 0; r < 8; ++r) {
    __syncthreads();
    const u16* bufr = stage[r & 1];
    bf16x8 fAh[2], fBh[2];
#pragma unroll
    for (int i = 0; i < 2; ++i) {
      fAh[i] = *(const bf16x8*)&bufr[fa + i*640];
      fBh[i] = *(const bf16x8*)&bufr[fb + i*640];
    }
    if (r + 1 < 8) {
      u16* bufw = stage[(r + 1) & 1];
      *(uint4*)&bufw[sA ] = rA;
      *(uint4*)&bufw[sB0] = rb0; *(uint4*)&bufw[sB1] = rb1;
      if (r + 2 < 8) {
        const int o = (r + 2) * 32;
        rA = *(const uint4*)(Ag + o);
        rb0 = *(const uint4*)(B0 + o); rb1 = *(const uint4*)(B1 + o);
      }
    }
    MFMA1(acc);
  }

  __syncthreads();
  {
    const int r0 = (lane>>4)<<2;
    const int c0 = wc*32 + (lane&15);
#pragma unroll
    for (int i = 0; i < 2; ++i)
#pragma unroll
      for (int j = 0; j < 2; ++j)
#pragma unroll
        for (int g = 0; g < 4; ++g)
          fbuf[kgw*2176 + (r0 + i*16 + g)*68 + c0 + j*16] = acc[i][j][g];
  }
  __syncthreads();
  const int erow = wave << 2;
#pragma unroll
  for (int r = 0; r < 4; ++r) {
    const int row = erow + r;
    float e = fbuf[row*68 + lane] + fbuf[2176 + row*68 + lane]
            + fbuf[4352 + row*68 + lane] + fbuf[6528 + row*68 + lane];
    float v_ = e * rinvl[row];
    const int s = mBase + row;
    out1h[(size_t)s*D_TOT + nBase + lane] = bf16rne(v_);
  }
}

// ================= final (round-8 verbatim): out = out1h @ wo.T + bo =================
__global__ __launch_bounds__(512,4) void final_mfma(
    const u16* __restrict__ out1h,
    const float* __restrict__ wo, const float* __restrict__ bo,
    float* __restrict__ out)
{
  __shared__ __align__(16) u16 stg[25600];
  float* fbuf = (float*)stg;
  const int t = threadIdx.x, lane = t & 63, wave = t >> 6;
  const int mBase = blockIdx.y << 5, nBase = blockIdx.x << 6;
  const int kg = t >> 7, sub = t & 127;
  const int arow = sub >> 2, acol = (sub & 3) << 3;
  const int brow0 = sub >> 2, bcol0 = (sub & 3) << 3;
  const int brow1 = (sub + 128) >> 2, bcol1 = ((sub + 128) & 3) << 3;
  const int kgw = wave >> 1, wc = wave & 1;

  const u16* Ag = out1h + (size_t)(mBase+arow)*D_TOT + acol + kg*128;
  const float* B0 = wo + (size_t)(nBase+brow0)*D_TOT + bcol0 + kg*128;
  const float* B1 = wo + (size_t)(nBase+brow1)*D_TOT + bcol1 + kg*128;

  const int sA  = kg*6400 + arow*40 + acol;
  const int sB0 = kg*6400 + 1280 + brow0*40 + bcol0;
  const int sB1 = kg*6400 + 1280 + brow1*40 + bcol1;
  const int fa  = kgw*6400 + (lane&15)*40 + ((lane>>4)<<3);
  const int fbh = kgw*6400 + 1280 + (wc*32 + (lane&15))*40 + ((lane>>4)<<3);

  uint4 rA = *(const uint4*)Ag;
  float4 b00 = *(const float4*)B0, b01 = *(const float4*)(B0 + 4);
  float4 b10 = *(const float4*)B1, b11 = *(const float4*)(B1 + 4);

  f32x4 zero = {0.f,0.f,0.f,0.f};
  f32x4 acc[2][2] = {{zero,zero},{zero,zero}};
#pragma unroll
  for (int r = 0; r < 4; ++r) {
    __syncthreads();
    uint4 bh0,bl0,bh1,bl1;
    bsplit8(b00,b01,bh0,bl0); bsplit8(b10,b11,bh1,bl1);
    *(uint4*)&stg[sA        ] = rA;
    *(uint4*)&stg[sB0       ] = bh0; *(uint4*)&stg[sB0 + 2560] = bl0;
    *(uint4*)&stg[sB1       ] = bh1; *(uint4*)&stg[sB1 + 2560] = bl1;
    if (r + 1 < 4) {
      const int o = (r + 1) * 32;
      rA = *(const uint4*)(Ag + o);
      b00 = *(const float4*)(B0 + o); b01 = *(const float4*)(B0 + o + 4);
      b10 = *(const float4*)(B1 + o); b11 = *(const float4*)(B1 + o + 4);
    }
    __syncthreads();
    bf16x8 fAh[2], fBh[2], fBl[2];
#pragma unroll
    for (int i = 0; i < 2; ++i) {
      fAh[i] = *(const bf16x8*)&stg[fa         + i*640];
      fBh[i] = *(const bf16x8*)&stg[fbh        + i*640];
      fBl[i] = *(const bf16x8*)&stg[fbh + 2560 + i*640];
    }
    MFMA2(acc);
  }

  __syncthreads();
  {
    const int r0 = (lane>>4)<<2;
    const int c0 = wc*32 + (lane&15);
#pragma unroll
    for (int i = 0; i < 2; ++i)
#pragma unroll
      for (int j = 0; j < 2; ++j)
#pragma unroll
        for (int g = 0; g < 4; ++g)
          fbuf[kgw*2176 + (r0 + i*16 + g)*68 + c0 + j*16] = acc[i][j][g];
  }
  __syncthreads();
  const int erow = wave << 2;
  const float b = bo[nBase + lane];
#pragma unroll
  for (int r = 0; r < 4; ++r) {
    const int row = erow + r;
    float e = fbuf[row*68 + lane] + fbuf[2176 + row*68 + lane]
            + fbuf[4352 + row*68 + lane] + fbuf[6528 + row*68 + lane];
    out[(size_t)(mBase+row)*D_TOT + nBase + lane] = e + b;
  }
}

extern "C" void kernel_launch(void* const* d_in, const int* in_sizes, int n_in,
                              void* d_out, int out_size, void* d_ws, size_t ws_size,
                              hipStream_t stream)
{
  const float* x   = (const float*)d_in[0];
  const float* wq  = (const float*)d_in[1];
  const float* bq  = (const float*)d_in[2];
  const float* wk  = (const float*)d_in[3];
  const float* bk  = (const float*)d_in[4];
  const float* wv  = (const float*)d_in[5];
  const float* bv  = (const float*)d_in[6];
  const float* wo  = (const float*)d_in[7];
  const float* bo  = (const float*)d_in[8];
  const float* alpha_u = (const float*)d_in[9];
  float* out = (float*)d_out;

  u16* U = (u16*)d_ws;
  u16* Qch   = U + 0;
  u16* Kch   = U + 524288;
  u16* vTh   = U + 1048576;
  u16* Eh    = U + 1572864;   // 1M
  u16* out1h = U + 2621440;
  float* F = (float*)(U + 3145728);
  float* qnpart  = F;          // [1024][8]
  float* knpart  = F + 8192;
  float* uh2a    = F + 16384;
  float* vh2a    = F + 17408;
  float* rowpart = F + 18432;  // [1024][16]

  qkv_mfma<<<dim3(8,16,3), 512, 0, stream>>>(x, wq,bq, wk,bk, wv,bv,
      Qch, Kch, vTh, qnpart, knpart, uh2a, vh2a);
  score_mfma<<<dim3(16,16), 512, 0, stream>>>(Qch, Kch,
      qnpart, knpart, uh2a, vh2a, alpha_u, Eh, rowpart);
  av_mfma<<<dim3(8,32), 512, 0, stream>>>(Eh, vTh, rowpart, out1h);
  final_mfma<<<dim3(8,32), 512, 0, stream>>>(out1h, wo, bo, out);
}

// Round 15
// 34.503 us; speedup vs baseline: 1.4827x; 1.1058x over previous
//
#include <hip/hip_runtime.h>

#define S_LEN 1024
#define D_TOT 512
#define D_E   448

typedef short bf16x8 __attribute__((ext_vector_type(8)));
typedef float f32x4  __attribute__((ext_vector_type(4)));
typedef unsigned short u16;

__device__ __forceinline__ float frcp(float x) {
  float r; asm("v_rcp_f32 %0, %1" : "=v"(r) : "v"(x)); return r;
}

__device__ __forceinline__ float wave_sum64(float v) {
#pragma unroll
  for (int o = 32; o > 0; o >>= 1) v += __shfl_xor(v, o);
  return v;
}

__device__ __forceinline__ u16 bf16rne(float f) {
  unsigned u = __builtin_bit_cast(unsigned, f);
  return (u16)((u + 0x7fffu + ((u >> 16) & 1u)) >> 16);
}

__device__ __forceinline__ uint4 rne8(float4 a, float4 b) {
  uint4 h;
  h.x = (unsigned)bf16rne(a.x) | ((unsigned)bf16rne(a.y)<<16);
  h.y = (unsigned)bf16rne(a.z) | ((unsigned)bf16rne(a.w)<<16);
  h.z = (unsigned)bf16rne(b.x) | ((unsigned)bf16rne(b.y)<<16);
  h.w = (unsigned)bf16rne(b.z) | ((unsigned)bf16rne(b.w)<<16);
  return h;
}

#define MFMA1(ACC)                                                                              \
  _Pragma("unroll") for (int i_ = 0; i_ < 2; ++i_)                                              \
  _Pragma("unroll") for (int j_ = 0; j_ < 2; ++j_)                                              \
    ACC[i_][j_] = __builtin_amdgcn_mfma_f32_16x16x32_bf16(fAh[i_], fBh[j_], ACC[i_][j_],0,0,0);

// ================= QKV: q/k/v = x @ W.T + b (all hi-only, MFMA1) =================
// 64x64 tile, 8 waves = 2(kg) x 2(wr) x 2(wc), BK=32, dbuf LDS 40960B.
__global__ __launch_bounds__(512,4) void qkv_mfma(
    const float* __restrict__ x,
    const float* __restrict__ wq, const float* __restrict__ bq,
    const float* __restrict__ wk, const float* __restrict__ bk,
    const float* __restrict__ wv, const float* __restrict__ bv,
    u16* __restrict__ Qch, u16* __restrict__ Kch, u16* __restrict__ vTh,
    float* __restrict__ qnpart, float* __restrict__ knpart,
    float* __restrict__ uh2a, float* __restrict__ vh2a)
{
  __shared__ __align__(16) u16 stage[2][10240];   // per buf: [2 kg][A 2560 | B 2560]
  float* fbuf = (float*)stage;                    // [2][64][68] overlay
  const int z = blockIdx.z;
  const float* W; const float* bias;
  if (z == 0)      { W = wq; bias = bq; }
  else if (z == 1) { W = wk; bias = bk; }
  else             { W = wv; bias = bv; }
  const int mBase = blockIdx.y << 6, nBase = blockIdx.x << 6;
  const int t = threadIdx.x, lane = t & 63, wave = t >> 6;
  const int kg = t >> 8, sub = t & 255;
  const int srow = sub >> 2, scol = (sub & 3) << 3;
  const int kgw = wave >> 2, wr = (wave >> 1) & 1, wc = wave & 1;

  const float* Ag = x + (size_t)(mBase + srow) * D_TOT + scol + kg * 256;
  const float* Bg = W + (size_t)(nBase + srow) * D_TOT + scol + kg * 256;

  const int sb = kg * 5120 + srow * 40 + scol;
  const int fa = kgw * 5120 + (wr * 32 + (lane & 15)) * 40 + ((lane >> 4) << 3);
  const int fb = kgw * 5120 + 2560 + (wc * 32 + (lane & 15)) * 40 + ((lane >> 4) << 3);

  float4 a0 = *(const float4*)Ag, a1 = *(const float4*)(Ag + 4);
  float4 b0 = *(const float4*)Bg, b1 = *(const float4*)(Bg + 4);
  *(uint4*)&stage[0][sb       ] = rne8(a0,a1);
  *(uint4*)&stage[0][sb + 2560] = rne8(b0,b1);
  a0 = *(const float4*)(Ag + 32); a1 = *(const float4*)(Ag + 36);
  b0 = *(const float4*)(Bg + 32); b1 = *(const float4*)(Bg + 36);

  f32x4 zero = {0.f,0.f,0.f,0.f};
  f32x4 acc[2][2] = {{zero,zero},{zero,zero}};
#pragma unroll
  for (int r = 0; r < 8; ++r) {
    __syncthreads();
    const u16* bufr = stage[r & 1];
    bf16x8 fAh[2], fBh[2];
#pragma unroll
    for (int i = 0; i < 2; ++i) {
      fAh[i] = *(const bf16x8*)&bufr[fa + i*640];
      fBh[i] = *(const bf16x8*)&bufr[fb + i*640];
    }
    if (r + 1 < 8) {
      u16* bufw = stage[(r + 1) & 1];
      *(uint4*)&bufw[sb       ] = rne8(a0,a1);
      *(uint4*)&bufw[sb + 2560] = rne8(b0,b1);
      if (r + 2 < 8) {
        const int o = (r + 2) * 32;
        a0 = *(const float4*)(Ag + o); a1 = *(const float4*)(Ag + o + 4);
        b0 = *(const float4*)(Bg + o); b1 = *(const float4*)(Bg + o + 4);
      }
    }
    MFMA1(acc);
  }

  __syncthreads();
  {
    const int r0 = wr*32 + ((lane>>4)<<2);
    const int c0 = wc*32 + (lane&15);
#pragma unroll
    for (int i = 0; i < 2; ++i)
#pragma unroll
      for (int j = 0; j < 2; ++j)
#pragma unroll
        for (int g = 0; g < 4; ++g)
          fbuf[kgw*4352 + (r0 + i*16 + g)*68 + c0 + j*16] = acc[i][j][g];
  }
  __syncthreads();
  const int erow = wave << 3;
  float val[8];
  {
    const float b = bias[nBase + lane];
#pragma unroll
    for (int r = 0; r < 8; ++r)
      val[r] = fbuf[(erow+r)*68 + lane] + fbuf[4352 + (erow+r)*68 + lane] + b;
  }

  if (z == 2) {
    u16 hh[8];
#pragma unroll
    for (int r = 0; r < 8; ++r) hh[r] = bf16rne(val[r]);
    const size_t off = (size_t)(nBase + lane) * S_LEN + mBase + erow;
    ushort4 p0{hh[0],hh[1],hh[2],hh[3]}, p1{hh[4],hh[5],hh[6],hh[7]};
    *(ushort4*)(vTh + off) = p0; *(ushort4*)(vTh + off + 4) = p1;
  } else {
    u16* Ch = z ? Kch : Qch;
    float* np_ = z ? knpart : qnpart;
    float* u2a = z ? vh2a  : uh2a;
    if (blockIdx.x < 7) {
#pragma unroll
      for (int r = 0; r < 8; ++r) {
        const int s = mBase + erow + r;
        Ch[(size_t)s*D_TOT + nBase + lane] = bf16rne(val[r]);
        float p = wave_sum64(val[r]*val[r]);
        if (lane == 0) np_[s*8 + blockIdx.x] = p;
      }
    } else {
#pragma unroll
      for (int r = 0; r < 8; ++r) {
        const int s = mBase + erow + r;
        float n2 = wave_sum64(val[r]*val[r]);
        float nn = sqrtf(n2);
        float n  = fmaxf(nn, 1e-5f);
        float e2n = __expf(2.f*n);
        float th  = 1.f - 2.f*frcp(e2n + 1.f);
        float rn  = frcp(n);
        float pn  = th * nn * rn;
        float scale = fminf(0.999f * frcp(fmaxf(pn, 1e-5f)), 1.f);
        float u = th * rn * scale * val[r];
        float un = pn * scale;
        Ch[(size_t)s*D_TOT + nBase + lane] = bf16rne(u);
        if (lane == 0) u2a[s] = un*un;
      }
    }
  }
}

// ================= score: Q hi x K hi (MFMA1), dbuf, 64x64 tile (round-14 verbatim) =================
__global__ __launch_bounds__(512,4) void score_mfma(
    const u16* __restrict__ Qch, const u16* __restrict__ Kch,
    const float* __restrict__ qnpart, const float* __restrict__ knpart,
    const float* __restrict__ uh2a, const float* __restrict__ vh2a,
    const float* __restrict__ alpha_u,
    u16* __restrict__ Eh, float* __restrict__ rowpart)
{
  __shared__ __align__(16) char shm_[69632];
  __shared__ float rowscal[256];
  u16* stg = (u16*)shm_;
  float* fbuf = (float*)shm_;
  const int t = threadIdx.x, lane = t & 63, wave = t >> 6;
  const int mBase = blockIdx.y << 6, nBase = blockIdx.x << 6;
  if (t < 64) {
    float s_ = 0.f;
#pragma unroll
    for (int c = 0; c < 7; ++c) s_ += qnpart[(mBase+t)*8 + c];
    rowscal[t] = s_;
  } else if (t < 128) {
    float s_ = 0.f;
#pragma unroll
    for (int c = 0; c < 7; ++c) s_ += knpart[(nBase+t-64)*8 + c];
    rowscal[t] = s_;
  } else if (t < 192) rowscal[t] = uh2a[mBase + t - 128];
  else if (t < 256)   rowscal[t] = vh2a[nBase + t - 192];

  const int kg = t >> 8, sub = t & 255;
  const int srow = sub >> 2, scol = (sub & 3) << 3;
  const int kgw = wave >> 2, wr = (wave >> 1) & 1, wc = wave & 1;
  const u16* Agh = Qch + (size_t)(mBase+srow)*D_TOT + scol;
  const u16* Bgh = Kch + (size_t)(nBase+srow)*D_TOT + scol;

  const int sb  = kg * 5120 + srow * 40 + scol;
  const int fa  = kgw * 5120 + (wr * 32 + (lane & 15)) * 40 + ((lane >> 4) << 3);
  const int fbh = kgw * 5120 + 2560 + (wc * 32 + (lane & 15)) * 40 + ((lane >> 4) << 3);

  int kb = kg * 224;
  uint4 rAh = *(const uint4*)(Agh + kb);
  uint4 rBh = *(const uint4*)(Bgh + kb);
  *(uint4*)&stg[sb       ] = rAh;
  *(uint4*)&stg[sb + 2560] = rBh;
  kb = kg * 224 + 32;
  rAh = *(const uint4*)(Agh + kb);
  rBh = *(const uint4*)(Bgh + kb);

  f32x4 zero = {0.f,0.f,0.f,0.f};
  f32x4 accE[2][2] = {{zero,zero},{zero,zero}};
  f32x4 accH[2][2] = {{zero,zero},{zero,zero}};
#pragma unroll
  for (int r = 0; r < 8; ++r) {
    __syncthreads();
    const u16* bufr = stg + (r & 1) * 10240;
    bf16x8 fAh[2], fBh[2];
#pragma unroll
    for (int i = 0; i < 2; ++i) {
      fAh[i] = *(const bf16x8*)&bufr[fa  + i*640];
      fBh[i] = *(const bf16x8*)&bufr[fbh + i*640];
    }
    if (r + 1 < 8) {
      u16* bufw = stg + ((r + 1) & 1) * 10240;
      *(uint4*)&bufw[sb       ] = rAh;
      *(uint4*)&bufw[sb + 2560] = rBh;
      if (r + 2 < 8) {
        const int o = (r + 2 < 7) ? (kg*224 + (r+2)*32) : (448 + kg*32);
        rAh = *(const uint4*)(Agh + o);
        rBh = *(const uint4*)(Bgh + o);
      }
    }
    if (r < 7) { MFMA1(accE) } else { MFMA1(accH) }
  }

  __syncthreads();
  {
    const int r0 = wr*32 + ((lane>>4)<<2);
    const int c0 = wc*32 + (lane&15);
#pragma unroll
    for (int i = 0; i < 2; ++i)
#pragma unroll
      for (int j = 0; j < 2; ++j)
#pragma unroll
        for (int g = 0; g < 4; ++g) {
          fbuf[       kgw*4352 + (r0 + i*16 + g)*68 + c0 + j*16] = accE[i][j][g];
          fbuf[8704 + kgw*4352 + (r0 + i*16 + g)*68 + c0 + j*16] = accH[i][j][g];
        }
  }
  __syncthreads();
  const int erow = wave << 3;
  float eE[8], eH[8];
#pragma unroll
  for (int r = 0; r < 8; ++r) {
    eE[r] = fbuf[(erow+r)*68 + lane] + fbuf[4352 + (erow+r)*68 + lane];
    eH[r] = fbuf[8704 + (erow+r)*68 + lane] + fbuf[8704 + 4352 + (erow+r)*68 + lane];
  }

  const float alpha = __logf(1.f + __expf(alpha_u[0]));
  const float inv_s = 0.04419417382415922f;
  const float knl = rowscal[64 + lane], v2 = rowscal[192 + lane];
#pragma unroll
  for (int r = 0; r < 8; ++r) {
    const int s = mBase + erow + r;
    const float qns = rowscal[erow + r], u2 = rowscal[128 + erow + r];
    float de   = qns + knl - 2.f * eE[r];
    float dH   = eH[r];
    float Ac   = 1.f - 2.f*dH + v2;
    float Bc   = 1.f - u2;
    float num2 = Ac*Ac*u2 + Bc*Bc*v2 - 2.f*Ac*Bc*dH;
    float den  = fmaxf(1.f - 2.f*dH + u2*v2, 1e-5f);
    float frac = sqrtf(fmaxf(num2, 0.f)) * frcp(den);
    float nrm  = fminf(frac, 0.999f);
    float dh_  = __logf((1.f + nrm) * frcp(1.f - nrm));
    float dist = de + alpha * dh_ * dh_;
    float lg   = fminf(fmaxf(-dist * inv_s, -50.f), 0.f);
    float e    = __expf(lg);
    Eh[(size_t)s*S_LEN + nBase + lane] = bf16rne(e);
    float rs = wave_sum64(e);
    if (lane == 0) rowpart[s*16 + blockIdx.x] = rs;
  }
}

// ================= av (round-14 verbatim): out1 = diag(rinv)*(E @ vT^T), MFMA1, dbuf =================
__global__ __launch_bounds__(512,4) void av_mfma(
    const u16* __restrict__ Eh, const u16* __restrict__ vTh,
    const float* __restrict__ rowpart,
    u16* __restrict__ out1h)
{
  __shared__ __align__(16) u16 stage[2][15360];
  __shared__ float rinvl[32];
  float* fbuf = (float*)stage;
  const int t = threadIdx.x, lane = t & 63, wave = t >> 6;
  const int mBase = blockIdx.y << 5, nBase = blockIdx.x << 6;
  if (t < 32) {
    float s_ = 0.f;
#pragma unroll
    for (int c = 0; c < 16; ++c) s_ += rowpart[(mBase+t)*16 + c];
    rinvl[t] = 1.f / s_;
  }
  const int kg = t >> 7, sub = t & 127;
  const int arow = sub >> 2, acol = (sub & 3) << 3;
  const int brow0 = sub >> 2, brow1 = 32 + (sub >> 2), bcol = (sub & 3) << 3;
  const int kgw = wave >> 1, wc = wave & 1;

  const u16* Ag = Eh  + (size_t)(mBase+arow)*S_LEN + kg*256 + acol;
  const u16* B0 = vTh + (size_t)(nBase+brow0)*S_LEN + kg*256 + bcol;
  const u16* B1 = vTh + (size_t)(nBase+brow1)*S_LEN + kg*256 + bcol;

  const int sA  = kg*3840 + arow*40 + acol;
  const int sB0 = kg*3840 + 1280 + brow0*40 + bcol;
  const int sB1 = kg*3840 + 1280 + brow1*40 + bcol;
  const int fa  = kgw*3840 + (lane&15)*40 + ((lane>>4)<<3);
  const int fb  = kgw*3840 + 1280 + (wc*32 + (lane&15))*40 + ((lane>>4)<<3);

  uint4 rA = *(const uint4*)Ag;
  uint4 rb0 = *(const uint4*)B0, rb1 = *(const uint4*)B1;
  *(uint4*)&stage[0][sA ] = rA;
  *(uint4*)&stage[0][sB0] = rb0; *(uint4*)&stage[0][sB1] = rb1;
  rA = *(const uint4*)(Ag + 32);
  rb0 = *(const uint4*)(B0 + 32); rb1 = *(const uint4*)(B1 + 32);

  f32x4 zero = {0.f,0.f,0.f,0.f};
  f32x4 acc[2][2] = {{zero,zero},{zero,zero}};
#pragma unroll
  for (int r = 0; r < 8; ++r) {
    __syncthreads();
    const u16* bufr = stage[r & 1];
    bf16x8 fAh[2], fBh[2];
#pragma unroll
    for (int i = 0; i < 2; ++i) {
      fAh[i] = *(const bf16x8*)&bufr[fa + i*640];
      fBh[i] = *(const bf16x8*)&bufr[fb + i*640];
    }
    if (r + 1 < 8) {
      u16* bufw = stage[(r + 1) & 1];
      *(uint4*)&bufw[sA ] = rA;
      *(uint4*)&bufw[sB0] = rb0; *(uint4*)&bufw[sB1] = rb1;
      if (r + 2 < 8) {
        const int o = (r + 2) * 32;
        rA = *(const uint4*)(Ag + o);
        rb0 = *(const uint4*)(B0 + o); rb1 = *(const uint4*)(B1 + o);
      }
    }
    MFMA1(acc);
  }

  __syncthreads();
  {
    const int r0 = (lane>>4)<<2;
    const int c0 = wc*32 + (lane&15);
#pragma unroll
    for (int i = 0; i < 2; ++i)
#pragma unroll
      for (int j = 0; j < 2; ++j)
#pragma unroll
        for (int g = 0; g < 4; ++g)
          fbuf[kgw*2176 + (r0 + i*16 + g)*68 + c0 + j*16] = acc[i][j][g];
  }
  __syncthreads();
  const int erow = wave << 2;
#pragma unroll
  for (int r = 0; r < 4; ++r) {
    const int row = erow + r;
    float e = fbuf[row*68 + lane] + fbuf[2176 + row*68 + lane]
            + fbuf[4352 + row*68 + lane] + fbuf[6528 + row*68 + lane];
    float v_ = e * rinvl[row];
    const int s = mBase + row;
    out1h[(size_t)s*D_TOT + nBase + lane] = bf16rne(v_);
  }
}

// ================= final: out = out1h @ wo.T + bo (wo hi-only, MFMA1, dbuf) =================
// 32x64 tile, 8 waves = 4(kg, K=128) x 2(wc), 4 steps of BK=32.
__global__ __launch_bounds__(512,4) void final_mfma(
    const u16* __restrict__ out1h,
    const float* __restrict__ wo, const float* __restrict__ bo,
    float* __restrict__ out)
{
  __shared__ __align__(16) u16 stage[2][15360];  // per buf: [4 kg][A 1280 | B 2560]
  float* fbuf = (float*)stage;
  const int t = threadIdx.x, lane = t & 63, wave = t >> 6;
  const int mBase = blockIdx.y << 5, nBase = blockIdx.x << 6;
  const int kg = t >> 7, sub = t & 127;
  const int arow = sub >> 2, acol = (sub & 3) << 3;
  const int brow0 = sub >> 2, brow1 = 32 + (sub >> 2), bcol = (sub & 3) << 3;
  const int kgw = wave >> 1, wc = wave & 1;

  const u16*   Ag = out1h + (size_t)(mBase+arow)*D_TOT + kg*128 + acol;
  const float* B0 = wo + (size_t)(nBase+brow0)*D_TOT + kg*128 + bcol;
  const float* B1 = wo + (size_t)(nBase+brow1)*D_TOT + kg*128 + bcol;

  const int sA  = kg*3840 + arow*40 + acol;
  const int sB0 = kg*3840 + 1280 + brow0*40 + bcol;
  const int sB1 = kg*3840 + 1280 + brow1*40 + bcol;
  const int fa  = kgw*3840 + (lane&15)*40 + ((lane>>4)<<3);
  const int fb  = kgw*3840 + 1280 + (wc*32 + (lane&15))*40 + ((lane>>4)<<3);

  uint4 rA = *(const uint4*)Ag;
  float4 b00 = *(const float4*)B0, b01 = *(const float4*)(B0 + 4);
  float4 b10 = *(const float4*)B1, b11 = *(const float4*)(B1 + 4);
  *(uint4*)&stage[0][sA ] = rA;
  *(uint4*)&stage[0][sB0] = rne8(b00,b01);
  *(uint4*)&stage[0][sB1] = rne8(b10,b11);
  rA = *(const uint4*)(Ag + 32);
  b00 = *(const float4*)(B0 + 32); b01 = *(const float4*)(B0 + 36);
  b10 = *(const float4*)(B1 + 32); b11 = *(const float4*)(B1 + 36);

  f32x4 zero = {0.f,0.f,0.f,0.f};
  f32x4 acc[2][2] = {{zero,zero},{zero,zero}};
#pragma unroll
  for (int r = 0; r < 4; ++r) {
    __syncthreads();
    const u16* bufr = stage[r & 1];
    bf16x8 fAh[2], fBh[2];
#pragma unroll
    for (int i = 0; i < 2; ++i) {
      fAh[i] = *(const bf16x8*)&bufr[fa + i*640];
      fBh[i] = *(const bf16x8*)&bufr[fb + i*640];
    }
    if (r + 1 < 4) {
      u16* bufw = stage[(r + 1) & 1];
      *(uint4*)&bufw[sA ] = rA;
      *(uint4*)&bufw[sB0] = rne8(b00,b01);
      *(uint4*)&bufw[sB1] = rne8(b10,b11);
      if (r + 2 < 4) {
        const int o = (r + 2) * 32;
        rA = *(const uint4*)(Ag + o);
        b00 = *(const float4*)(B0 + o); b01 = *(const float4*)(B0 + o + 4);
        b10 = *(const float4*)(B1 + o); b11 = *(const float4*)(B1 + o + 4);
      }
    }
    MFMA1(acc);
  }

  __syncthreads();
  {
    const int r0 = (lane>>4)<<2;
    const int c0 = wc*32 + (lane&15);
#pragma unroll
    for (int i = 0; i < 2; ++i)
#pragma unroll
      for (int j = 0; j < 2; ++j)
#pragma unroll
        for (int g = 0; g < 4; ++g)
          fbuf[kgw*2176 + (r0 + i*16 + g)*68 + c0 + j*16] = acc[i][j][g];
  }
  __syncthreads();
  const int erow = wave << 2;
  const float b = bo[nBase + lane];
#pragma unroll
  for (int r = 0; r < 4; ++r) {
    const int row = erow + r;
    float e = fbuf[row*68 + lane] + fbuf[2176 + row*68 + lane]
            + fbuf[4352 + row*68 + lane] + fbuf[6528 + row*68 + lane];
    out[(size_t)(mBase+row)*D_TOT + nBase + lane] = e + b;
  }
}

extern "C" void kernel_launch(void* const* d_in, const int* in_sizes, int n_in,
                              void* d_out, int out_size, void* d_ws, size_t ws_size,
                              hipStream_t stream)
{
  const float* x   = (const float*)d_in[0];
  const float* wq  = (const float*)d_in[1];
  const float* bq  = (const float*)d_in[2];
  const float* wk  = (const float*)d_in[3];
  const float* bk  = (const float*)d_in[4];
  const float* wv  = (const float*)d_in[5];
  const float* bv  = (const float*)d_in[6];
  const float* wo  = (const float*)d_in[7];
  const float* bo  = (const float*)d_in[8];
  const float* alpha_u = (const float*)d_in[9];
  float* out = (float*)d_out;

  u16* U = (u16*)d_ws;
  u16* Qch   = U + 0;
  u16* Kch   = U + 524288;
  u16* vTh   = U + 1048576;
  u16* Eh    = U + 1572864;
  u16* out1h = U + 2621440;
  float* F = (float*)(U + 3145728);
  float* qnpart  = F;
  float* knpart  = F + 8192;
  float* uh2a    = F + 16384;
  float* vh2a    = F + 17408;
  float* rowpart = F + 18432;

  qkv_mfma<<<dim3(8,16,3), 512, 0, stream>>>(x, wq,bq, wk,bk, wv,bv,
      Qch, Kch, vTh, qnpart, knpart, uh2a, vh2a);
  score_mfma<<<dim3(16,16), 512, 0, stream>>>(Qch, Kch,
      qnpart, knpart, uh2a, vh2a, alpha_u, Eh, rowpart);
  av_mfma<<<dim3(8,32), 512, 0, stream>>>(Eh, vTh, rowpart, out1h);
  final_mfma<<<dim3(8,32), 512, 0, stream>>>(out1h, wo, bo, out);
}